// Round 11
// baseline (430.556 us; speedup 1.0000x reference)
//
#include <hip/hip_runtime.h>
#include <hip/hip_bf16.h>
#include <math.h>

#define N_NODES 100000
#define N_EDGES 1600000
#define N_USER  90000
#define NBUCK   256
#define BSZ     352   // targets per bucket; 256*352 = 90112 >= N_USER
#define TILE    2048  // edges per bucket/bhist block
#define TBLK    782   // (N_EDGES + TILE - 1) / TILE
#define ACCB    22500 // N_USER / 4
#define HPB     1024  // hp base grid (per layer)

typedef __attribute__((ext_vector_type(8))) short  short8;   // 8 bf16 (4 VGPRs) MFMA A/B frag
typedef __attribute__((ext_vector_type(4))) float  floatx4;  // MFMA C/D frag
typedef unsigned int  uint;
typedef unsigned short ushort;

__device__ __forceinline__ ushort f2bf(float x) {            // RNE fp32 -> bf16
  uint u = __float_as_uint(x);
  u += 0x7fffu + ((u >> 16) & 1u);
  return (ushort)(u >> 16);
}
__device__ __forceinline__ float bf2f(ushort v) { return __uint_as_float(((uint)v) << 16); }

__device__ __forceinline__ void split8(const float v[8], short8& hi, short8& lo) {
  #pragma unroll
  for (int j = 0; j < 8; ++j) {
    ushort h = f2bf(v[j]);
    hi[j] = (short)h;
    lo[j] = (short)f2bf(v[j] - bf2f(h));
  }
}
__device__ __forceinline__ void load_split8(const float* p, short8& hi, short8& lo) {
  const float4* q = (const float4*)p;
  float4 a = q[0], b = q[1];
  float v[8] = {a.x, a.y, a.z, a.w, b.x, b.y, b.z, b.w};
  split8(v, hi, lo);
}
__device__ __forceinline__ float fast_tanh(float x) {
  float t = __expf(2.f * x);
  return 1.f - 2.f / (t + 1.f);
}

// ---------------- stage1: hp (MFMA) for both layers  ||  bhist for both layers ----------
__global__ __launch_bounds__(256) void stage1(
    const float* __restrict__ h,
    const float* __restrict__ wA,  const float* __restrict__ wB,
    const float* __restrict__ asA, const float* __restrict__ asB,
    const float* __restrict__ atA, const float* __restrict__ atB,
    uint* __restrict__ hpiA, uint* __restrict__ hpiB,
    float* __restrict__ attnsA, float* __restrict__ attnsB,
    float* __restrict__ attntA, float* __restrict__ attntB,
    const int* __restrict__ trgA, const int* __restrict__ trgB,
    int* __restrict__ bhist,
    int hpTot, int hpBase, int bhBase)
{
  __shared__ float part[4][16][4];          // hp: [wave][row][as0,as1,at0,at1]
  __shared__ int hh[NBUCK];                 // bhist
  const int tid = threadIdx.x;

  if (blockIdx.x >= hpTot) {                // ---- bhist branch ----
    const int b2 = blockIdx.x - hpTot;
    const int layer = (b2 >= bhBase) ? 1 : 0;
    const int bid = b2 - layer * bhBase;
    const int* trg = layer ? trgB : trgA;
    int* bh = bhist + layer * NBUCK;
    hh[tid] = 0;
    __syncthreads();
    const int b0 = bid * TILE;
    #pragma unroll
    for (int j = 0; j < 8; ++j) {
      int e = b0 + j * 256 + tid;
      if (e < N_EDGES) {
        int t = trg[e];
        if (t < N_USER) atomicAdd(&hh[t / BSZ], 1);
      }
    }
    __syncthreads();
    if (hh[tid]) atomicAdd(&bh[tid], hh[tid]);
    return;
  }

  // ---- hp branch ----
  const int layer = (blockIdx.x >= hpBase) ? 1 : 0;
  const int bid = blockIdx.x - layer * hpBase;
  const float* w     = layer ? wB : wA;
  const float* a_src = layer ? asB : asA;
  const float* a_trg = layer ? atB : atA;
  uint*  hpi      = layer ? hpiB : hpiA;
  float* attn_src = layer ? attnsB : attnsA;
  float* attn_trg = layer ? attntB : attntA;

  const int lane = tid & 63, wv = tid >> 6;
  const int quad = lane >> 4, l15 = lane & 15;
  const int o = wv * 16 + l15;              // wave's 16-col slice of the 64 outputs
  const float vas0 = a_src[o], vas1 = a_src[64 + o];
  const float vat0 = a_trg[o], vat1 = a_trg[64 + o];
  short8 b0h[2], b0l[2], b1h[2], b1l[2];    // B frags: head0/head1 x ksteps
  #pragma unroll
  for (int ks = 0; ks < 2; ++ks) {
    float v0[8], v1[8];
    #pragma unroll
    for (int j = 0; j < 8; ++j) {
      int k = quad * 8 + j + ks * 32;       // f index
      v0[j] = w[k * 64 + o];                // w[0][f][o]
      v1[j] = w[4096 + k * 64 + o];         // w[1][f][o]
    }
    split8(v0, b0h[ks], b0l[ks]);
    split8(v1, b1h[ks], b1l[ks]);
  }
  for (int t = bid; t < N_NODES / 16; t += hpBase) {
    int m0 = t * 16, arow = m0 + l15;
    short8 ah[2], al[2];
    #pragma unroll
    for (int ks = 0; ks < 2; ++ks)
      load_split8(h + arow * 64 + quad * 8 + ks * 32, ah[ks], al[ks]);
    floatx4 c0 = {0.f, 0.f, 0.f, 0.f}, c1 = {0.f, 0.f, 0.f, 0.f};
    #pragma unroll
    for (int ks = 0; ks < 2; ++ks) {
      c0 = __builtin_amdgcn_mfma_f32_16x16x32_bf16(ah[ks], b0h[ks], c0, 0, 0, 0);
      c0 = __builtin_amdgcn_mfma_f32_16x16x32_bf16(ah[ks], b0l[ks], c0, 0, 0, 0);
      c0 = __builtin_amdgcn_mfma_f32_16x16x32_bf16(al[ks], b0h[ks], c0, 0, 0, 0);
      c1 = __builtin_amdgcn_mfma_f32_16x16x32_bf16(ah[ks], b1h[ks], c1, 0, 0, 0);
      c1 = __builtin_amdgcn_mfma_f32_16x16x32_bf16(ah[ks], b1l[ks], c1, 0, 0, 0);
      c1 = __builtin_amdgcn_mfma_f32_16x16x32_bf16(al[ks], b1h[ks], c1, 0, 0, 0);
    }
    #pragma unroll
    for (int r = 0; r < 4; ++r) {
      int n = m0 + quad * 4 + r;
      hpi[n * 64 + o] = (uint)f2bf(c0[r]) | ((uint)f2bf(c1[r]) << 16);
    }
    #pragma unroll
    for (int r = 0; r < 4; ++r) {
      float pas0 = c0[r] * vas0, pas1 = c1[r] * vas1;
      float pat0 = c0[r] * vat0, pat1 = c1[r] * vat1;
      #pragma unroll
      for (int m = 1; m < 16; m <<= 1) {
        pas0 += __shfl_xor(pas0, m, 64); pas1 += __shfl_xor(pas1, m, 64);
        pat0 += __shfl_xor(pat0, m, 64); pat1 += __shfl_xor(pat1, m, 64);
      }
      if (l15 == 0) {
        part[wv][quad * 4 + r][0] = pas0; part[wv][quad * 4 + r][1] = pas1;
        part[wv][quad * 4 + r][2] = pat0; part[wv][quad * 4 + r][3] = pat1;
      }
    }
    __syncthreads();
    if (tid < 64) {
      int row = tid & 15, which = tid >> 4;
      float v = part[0][row][which] + part[1][row][which]
              + part[2][row][which] + part[3][row][which];
      int n = m0 + row;
      if (which == 0)      attn_src[n * 2]     = v;
      else if (which == 1) attn_src[n * 2 + 1] = v;
      else if (which == 2) attn_trg[n * 2]     = v;
      else                 attn_trg[n * 2 + 1] = v;
    }
    __syncthreads();
  }
}

// 1-block-per-layer scan of the 256 bucket sizes -> bstart[257] + seeded bucket cursors.
__global__ __launch_bounds__(256) void scanb2(const int* __restrict__ bhist,
                                              int* __restrict__ bstart, int* __restrict__ bcur)
{
  const int layer = blockIdx.x;
  const int* bh = bhist + layer * NBUCK;
  int* bs = bstart + layer * (NBUCK + 1);
  int* bc = bcur + layer * NBUCK * 16;
  __shared__ int s[256];
  int v = bh[threadIdx.x];
  s[threadIdx.x] = v;
  __syncthreads();
  for (int d = 1; d < 256; d <<= 1) {
    int t = (threadIdx.x >= d) ? s[threadIdx.x - d] : 0;
    __syncthreads();
    s[threadIdx.x] += t;
    __syncthreads();
  }
  int excl = s[threadIdx.x] - v;
  bs[threadIdx.x] = excl;
  bc[threadIdx.x * 16] = excl;
  if (threadIdx.x == 255) bs[256] = s[255];
}

// Pass B: bin a 2048-edge tile by bucket in LDS, bulk-append contiguous runs per bucket.
// Packed pairbuf: src (17b) | bucket-local trg (9b); bucket id rides in LDS.
__global__ __launch_bounds__(256) void bucket2(
    const int* __restrict__ srcA, const int* __restrict__ srcB,
    const int* __restrict__ trgA, const int* __restrict__ trgB,
    int* __restrict__ bcur, uint* __restrict__ pairbufA, uint* __restrict__ pairbufB, int base)
{
  const int layer = (blockIdx.x >= base) ? 1 : 0;
  const int bid = blockIdx.x - layer * base;
  const int* src = layer ? srcB : srcA;
  const int* trg = layer ? trgB : trgA;
  int* bc = bcur + layer * NBUCK * 16;
  uint* pairbuf = layer ? pairbufB : pairbufA;

  __shared__ uint2 plds[TILE];              // (packed entry, bucket id)
  __shared__ int bcnt[NBUCK], bscan[NBUCK], gbase[NBUCK];
  const int tid = threadIdx.x;
  const int b0 = bid * TILE;
  bcnt[tid] = 0;
  __syncthreads();
  int myb[8], myr[8];
  uint myp[8];
  #pragma unroll
  for (int j = 0; j < 8; ++j) {
    int e = b0 + j * 256 + tid;
    myb[j] = -1;
    if (e < N_EDGES) {
      int t = trg[e];
      if (t < N_USER) {
        int b = t / BSZ;
        int tl = t - b * BSZ;               // < 352, fits 9 bits
        myb[j] = b;
        myr[j] = atomicAdd(&bcnt[b], 1);
        myp[j] = (uint)src[e] | ((uint)tl << 17);   // src < 2^17
      }
    }
  }
  __syncthreads();
  gbase[tid] = atomicAdd(&bc[tid * 16], bcnt[tid]);
  bscan[tid] = bcnt[tid];
  __syncthreads();
  for (int d = 1; d < 256; d <<= 1) {
    int v = (tid >= d) ? bscan[tid - d] : 0;
    __syncthreads();
    bscan[tid] += v;
    __syncthreads();
  }
  #pragma unroll
  for (int j = 0; j < 8; ++j)
    if (myb[j] >= 0) plds[bscan[myb[j]] - bcnt[myb[j]] + myr[j]] = make_uint2(myp[j], (uint)myb[j]);
  __syncthreads();
  int total = bscan[NBUCK - 1];
  for (int i = tid; i < total; i += 256) {
    uint2 pr = plds[i];
    int b = (int)pr.y;
    int idx = gbase[b] + (i - (bscan[b] - bcnt[b]));
    if (idx >= 0 && idx < N_EDGES) pairbuf[idx] = pr.x;
  }
}

// Pass C: one block per bucket (x2 layers), 1024 threads. Per-target offs in LDS.
__global__ __launch_bounds__(1024) void fine2(
    const uint* __restrict__ pairbufA, const uint* __restrict__ pairbufB,
    const int* __restrict__ bstart,
    int* __restrict__ offsA, int* __restrict__ offsB,
    int* __restrict__ csrA,  int* __restrict__ csrB,
    const float* __restrict__ attnsA, const float* __restrict__ attnsB,
    const float* __restrict__ attntA, const float* __restrict__ attntB,
    float2* __restrict__ wgtA, float2* __restrict__ wgtB, int base)
{
  const int layer = (blockIdx.x >= base) ? 1 : 0;
  const int b = blockIdx.x - layer * base;
  const uint* pairbuf = layer ? pairbufB : pairbufA;
  const int* bs = bstart + layer * (NBUCK + 1);
  int* offs = layer ? offsB : offsA;
  int* csr_src = layer ? csrB : csrA;
  const float* attn_src = layer ? attnsB : attnsA;
  const float* attn_trg = layer ? attntB : attntA;
  float2* wgt = layer ? wgtB : wgtA;

  __shared__ int cnt[BSZ + 1];
  __shared__ int cur[BSZ];
  const int tid = threadIdx.x;
  const int t0 = b * BSZ;
  const int nt = min(BSZ, N_USER - t0);     // 240 for bucket 255
  const int pbeg = bs[b], pend = bs[b + 1];
  for (int j = tid; j <= BSZ; j += 1024) cnt[j] = 0;
  __syncthreads();
  for (int i = pbeg + tid; i < pend; i += 1024) {
    int tl = min((int)(pairbuf[i] >> 17), BSZ - 1);
    atomicAdd(&cnt[tl], 1);
  }
  __syncthreads();
  if (tid == 0) {                           // serial exclusive scan, <=352 elems
    int run = 0;
    for (int j = 0; j < nt; ++j) { int c = cnt[j]; cnt[j] = run; run += c; }
    cnt[nt] = run;
  }
  __syncthreads();
  for (int j = tid; j < nt; j += 1024) {
    offs[t0 + j] = pbeg + cnt[j];
    cur[j] = cnt[j];
  }
  if (tid == 0 && t0 + nt == N_USER) offs[N_USER] = pbeg + cnt[nt];
  __syncthreads();
  const float2* as2 = (const float2*)attn_src;
  const float2* at2 = (const float2*)attn_trg;
  for (int i = pbeg + tid; i < pend; i += 1024) {
    uint v = pairbuf[i];
    int s = min((int)(v & 0x1FFFFu), N_NODES - 1);
    int tl = min((int)(v >> 17), BSZ - 1);
    int tt = min(t0 + tl, N_USER - 1);
    float2 as = as2[s];
    float2 at = at2[tt];
    float e0 = as.x + at.x; e0 = (e0 > 0.f) ? e0 : 0.2f * e0;
    float e1 = as.y + at.y; e1 = (e1 > 0.f) ? e1 : 0.2f * e1;
    int p = pbeg + atomicAdd(&cur[tl], 1);
    p = min(max(p, 0), N_EDGES - 1);
    csr_src[p] = s;
    wgt[p] = make_float2(__expf(e0), __expf(e1));
  }
}

// ---------------- R23: fused accum + final ----------------
// Block owns 16 users. Phase A: each wave runs the R9-proven scalarized accum loop 8x
// (4 users x 2 layers), x values land in LDS (row-padded to 68 floats, <=2-way bank
// aliasing). Phase B: final_mfma's math verbatim, A-frags + epilogue read from LDS.
// Saves the entire x0/x1 round trip (45 MB write + ~70 MB read) and one kernel boundary;
// final's latency-bound compute overlaps the gather stream across blocks.
__global__ __launch_bounds__(256) void accfin(
    const int* __restrict__ offs0, const int* __restrict__ offs1,
    const int* __restrict__ csr0,  const int* __restrict__ csr1,
    const float2* __restrict__ wgt0, const float2* __restrict__ wgt1,
    const uint* __restrict__ hpi0, const uint* __restrict__ hpi1,
    const float* __restrict__ h,
    const float* __restrict__ aa_w1, const float* __restrict__ aa_w2,
    const float* __restrict__ aa_m,
    const float* __restrict__ fc_w, const float* __restrict__ fc_b,
    float* __restrict__ out)
{
  __shared__ float xs[2][16][68];           // padded: stride 68 floats
  __shared__ float aam_s[64], fcw_s[384], fcb_s[2];
  __shared__ float scw0[4][16], scw1[4][16];
  const int tid = threadIdx.x;
  const int lane = tid & 63, wv = tid >> 6, quad = lane >> 4, l15 = lane & 15;
  const int m0 = blockIdx.x * 16;
  if (tid < 64)  aam_s[tid] = aa_m[tid];
  for (int i = tid; i < 384; i += 256) fcw_s[i] = fc_w[i];
  if (tid < 2)   fcb_s[tid] = fc_b[tid];

  // ---- Phase A: accumulate both layers for this block's 16 users (R9 loop verbatim) ----
  #pragma unroll
  for (int li = 0; li < 2; ++li) {
    const int* offs = li ? offs1 : offs0;
    const int* csr_src = li ? csr1 : csr0;
    const float2* wgt = li ? wgt1 : wgt0;
    const uint* hpi = li ? hpi1 : hpi0;
    for (int k = 0; k < 4; ++k) {
      int n = m0 + wv * 4 + k;
      int beg = max(0, offs[n]);
      int end = min(offs[n + 1], N_EDGES);
      beg = __builtin_amdgcn_readfirstlane(beg);
      end = __builtin_amdgcn_readfirstlane(end);
      int deg = end - beg;
      float acc0 = 0.f, acc1 = 0.f, den0 = 0.f, den1 = 0.f;
      for (int base2 = 0; base2 < deg; base2 += 64) {
        int rem = min(64, deg - base2);
        int sv = csr_src[beg + base2 + min(lane, rem - 1)];
        sv = min(max(sv, 0), N_NODES - 1);
        int nfull = rem & ~7;
        for (int j = 0; j < nfull; j += 8) {             // lean full blocks
          int ss[8]; uint pv[8]; float2 W[8];
          #pragma unroll
          for (int u = 0; u < 8; ++u) ss[u] = __builtin_amdgcn_readlane(sv, j + u);
          #pragma unroll
          for (int u = 0; u < 8; ++u) pv[u] = (hpi + (size_t)ss[u] * 64)[lane];
          #pragma unroll
          for (int u = 0; u < 8; ++u) W[u] = wgt[beg + base2 + j + u];
          #pragma unroll
          for (int u = 0; u < 8; ++u) {
            den0 += W[u].x; den1 += W[u].y;
            acc0 += W[u].x * bf2f((ushort)(pv[u] & 0xffffu));
            acc1 += W[u].y * bf2f((ushort)(pv[u] >> 16));
          }
        }
        if (nfull < rem) {                               // single masked tail block
          int j = nfull;
          int ss[8]; uint pv[8]; float2 W[8];
          #pragma unroll
          for (int u = 0; u < 8; ++u) ss[u] = __builtin_amdgcn_readlane(sv, min(j + u, rem - 1));
          #pragma unroll
          for (int u = 0; u < 8; ++u) pv[u] = (hpi + (size_t)ss[u] * 64)[lane];
          #pragma unroll
          for (int u = 0; u < 8; ++u)
            W[u] = (j + u < rem) ? wgt[beg + base2 + j + u] : make_float2(0.f, 0.f);
          #pragma unroll
          for (int u = 0; u < 8; ++u) {
            den0 += W[u].x; den1 += W[u].y;
            acc0 += W[u].x * bf2f((ushort)(pv[u] & 0xffffu));
            acc1 += W[u].y * bf2f((ushort)(pv[u] >> 16));
          }
        }
      }
      xs[li][wv * 4 + k][lane] = 0.5f * (acc0 / (den0 + 1e-16f) + acc1 / (den1 + 1e-16f));
    }
  }
  __syncthreads();

  // ---- Phase B: final math (final_mfma verbatim, x from LDS) ----
  const int d = wv * 16 + l15;
  short8 b1h[2], b1l[2], b2h[2], b2l[2];
  #pragma unroll
  for (int ks = 0; ks < 2; ++ks) {
    load_split8(aa_w1 + d * 64 + quad * 8 + ks * 32, b1h[ks], b1l[ks]);
    load_split8(aa_w2 + d * 64 + quad * 8 + ks * 32, b2h[ks], b2l[ks]);
  }
  const int arow = m0 + l15;
  const int erw = wv * 4 + quad;            // local epilogue row
  float4 ev0 = *(const float4*)&xs[0][erw][l15 * 4];
  float4 ev1 = *(const float4*)&xs[1][erw][l15 * 4];
  short8 ahh[2], ahl[2], a0h[2], a0l[2], a1h[2], a1l[2];
  #pragma unroll
  for (int ks = 0; ks < 2; ++ks) {
    load_split8(h + arow * 64 + quad * 8 + ks * 32, ahh[ks], ahl[ks]);
    load_split8(&xs[0][l15][quad * 8 + ks * 32], a0h[ks], a0l[ks]);
    load_split8(&xs[1][l15][quad * 8 + ks * 32], a1h[ks], a1l[ks]);
  }
  floatx4 t1a = {0.f,0.f,0.f,0.f}, t20a = {0.f,0.f,0.f,0.f}, t21a = {0.f,0.f,0.f,0.f};
  #pragma unroll
  for (int ks = 0; ks < 2; ++ks) {
    t1a  = __builtin_amdgcn_mfma_f32_16x16x32_bf16(ahh[ks], b1h[ks], t1a, 0, 0, 0);
    t1a  = __builtin_amdgcn_mfma_f32_16x16x32_bf16(ahh[ks], b1l[ks], t1a, 0, 0, 0);
    t1a  = __builtin_amdgcn_mfma_f32_16x16x32_bf16(ahl[ks], b1h[ks], t1a, 0, 0, 0);
    t20a = __builtin_amdgcn_mfma_f32_16x16x32_bf16(a0h[ks], b2h[ks], t20a, 0, 0, 0);
    t20a = __builtin_amdgcn_mfma_f32_16x16x32_bf16(a0h[ks], b2l[ks], t20a, 0, 0, 0);
    t20a = __builtin_amdgcn_mfma_f32_16x16x32_bf16(a0l[ks], b2h[ks], t20a, 0, 0, 0);
    t21a = __builtin_amdgcn_mfma_f32_16x16x32_bf16(a1h[ks], b2h[ks], t21a, 0, 0, 0);
    t21a = __builtin_amdgcn_mfma_f32_16x16x32_bf16(a1h[ks], b2l[ks], t21a, 0, 0, 0);
    t21a = __builtin_amdgcn_mfma_f32_16x16x32_bf16(a1l[ks], b2h[ks], t21a, 0, 0, 0);
  }
  float am = aam_s[d];
  #pragma unroll
  for (int r = 0; r < 4; ++r) {
    float q0 = fast_tanh(t1a[r] + t20a[r]);
    float q1 = fast_tanh(t1a[r] + t21a[r]);
    float p0 = q0 * am, p1 = q1 * am;
    #pragma unroll
    for (int m = 1; m < 16; m <<= 1) { p0 += __shfl_xor(p0, m, 64); p1 += __shfl_xor(p1, m, 64); }
    if (l15 == 0) { scw0[wv][quad * 4 + r] = p0; scw1[wv][quad * 4 + r] = p1; }
  }
  __syncthreads();
  {
    int row = wv * 4 + quad, n = m0 + row;
    float s0 = scw0[0][row] + scw0[1][row] + scw0[2][row] + scw0[3][row];
    float s1 = scw1[0][row] + scw1[1][row] + scw1[2][row] + scw1[3][row];
    float mx = fmaxf(s0, s1);
    float e0 = __expf(s0 - mx), e1 = __expf(s1 - mx);
    float inv = 1.f / (e0 + e1);
    float b0 = e0 * inv, b1 = e1 * inv;
    float a0[4] = {ev0.x, ev0.y, ev0.z, ev0.w};
    float a1[4] = {ev1.x, ev1.y, ev1.z, ev1.w};
    float pc0 = 0.f, pc1 = 0.f;
    #pragma unroll
    for (int c = 0; c < 4; ++c) {
      int o = l15 * 4 + c;
      float fv = b0 * a0[c] + b1 * a1[c];
      pc0 += fcw_s[o] * a0[c] + fcw_s[64 + o] * a1[c] + fcw_s[128 + o] * fv;
      pc1 += fcw_s[192 + o] * a0[c] + fcw_s[256 + o] * a1[c] + fcw_s[320 + o] * fv;
    }
    #pragma unroll
    for (int m = 1; m < 16; m <<= 1) { pc0 += __shfl_xor(pc0, m, 64); pc1 += __shfl_xor(pc1, m, 64); }
    if (l15 == 0) {
      float l0 = pc0 + fcb_s[0], l1 = pc1 + fcb_s[1];
      float lm = fmaxf(l0, l1);
      float lse = lm + logf(__expf(l0 - lm) + __expf(l1 - lm));
      out[n * 2] = l0 - lse;
      out[n * 2 + 1] = l1 - lse;
    }
  }
}

// ---------------- fallback-only kernels (ws-tight sequential path) ----------------
__global__ __launch_bounds__(256) void accum2(
    const int* __restrict__ offsA, const int* __restrict__ offsB,
    const int* __restrict__ csrA,  const int* __restrict__ csrB,
    const float2* __restrict__ wgtA, const float2* __restrict__ wgtB,
    const uint* __restrict__ hpiA, const uint* __restrict__ hpiB,
    float* __restrict__ xA, float* __restrict__ xB, int base, int swz)
{
  int layer, bid;
  if (swz) {
    const int xcd = blockIdx.x & 7, idx = blockIdx.x >> 3;
    layer = xcd >> 2;
    bid = idx * 4 + (xcd & 3);
  } else {
    layer = (blockIdx.x >= base) ? 1 : 0;
    bid = blockIdx.x - layer * base;
  }
  const int* offs = layer ? offsB : offsA;
  const int* csr_src = layer ? csrB : csrA;
  const float2* wgt = layer ? wgtB : wgtA;
  const uint* hpi = layer ? hpiB : hpiA;
  float* x = layer ? xB : xA;

  const int lane = threadIdx.x & 63, wv = threadIdx.x >> 6;
  int n = bid * 4 + wv;
  if (n >= N_USER) return;
  int beg = max(0, offs[n]);
  int end = min(offs[n + 1], N_EDGES);
  beg = __builtin_amdgcn_readfirstlane(beg);
  end = __builtin_amdgcn_readfirstlane(end);
  int deg = end - beg;
  float acc0 = 0.f, acc1 = 0.f, den0 = 0.f, den1 = 0.f;
  for (int base2 = 0; base2 < deg; base2 += 64) {
    int rem = min(64, deg - base2);
    int sv = csr_src[beg + base2 + min(lane, rem - 1)];
    sv = min(max(sv, 0), N_NODES - 1);
    int nfull = rem & ~7;
    for (int j = 0; j < nfull; j += 8) {
      int ss[8]; uint pv[8]; float2 W[8];
      #pragma unroll
      for (int u = 0; u < 8; ++u) ss[u] = __builtin_amdgcn_readlane(sv, j + u);
      #pragma unroll
      for (int u = 0; u < 8; ++u) pv[u] = (hpi + (size_t)ss[u] * 64)[lane];
      #pragma unroll
      for (int u = 0; u < 8; ++u) W[u] = wgt[beg + base2 + j + u];
      #pragma unroll
      for (int u = 0; u < 8; ++u) {
        den0 += W[u].x; den1 += W[u].y;
        acc0 += W[u].x * bf2f((ushort)(pv[u] & 0xffffu));
        acc1 += W[u].y * bf2f((ushort)(pv[u] >> 16));
      }
    }
    if (nfull < rem) {
      int j = nfull;
      int ss[8]; uint pv[8]; float2 W[8];
      #pragma unroll
      for (int u = 0; u < 8; ++u) ss[u] = __builtin_amdgcn_readlane(sv, min(j + u, rem - 1));
      #pragma unroll
      for (int u = 0; u < 8; ++u) pv[u] = (hpi + (size_t)ss[u] * 64)[lane];
      #pragma unroll
      for (int u = 0; u < 8; ++u)
        W[u] = (j + u < rem) ? wgt[beg + base2 + j + u] : make_float2(0.f, 0.f);
      #pragma unroll
      for (int u = 0; u < 8; ++u) {
        den0 += W[u].x; den1 += W[u].y;
        acc0 += W[u].x * bf2f((ushort)(pv[u] & 0xffffu));
        acc1 += W[u].y * bf2f((ushort)(pv[u] >> 16));
      }
    }
  }
  x[n * 64 + lane] = 0.5f * (acc0 / (den0 + 1e-16f) + acc1 / (den1 + 1e-16f));
}

__global__ __launch_bounds__(256) void final_mfma(
    const float* __restrict__ h, const float* __restrict__ x0, const float* __restrict__ x1,
    const float* __restrict__ aa_w1, const float* __restrict__ aa_w2, const float* __restrict__ aa_m,
    const float* __restrict__ fc_w, const float* __restrict__ fc_b, float* __restrict__ out)
{
  __shared__ float aam_s[64], fcw_s[384], fcb_s[2];
  __shared__ float scw0[2][4][16], scw1[2][4][16];
  const int tid = threadIdx.x;
  if (tid < 64)  aam_s[tid] = aa_m[tid];
  for (int i = tid; i < 384; i += 256) fcw_s[i] = fc_w[i];
  if (tid < 2)   fcb_s[tid] = fc_b[tid];
  const int lane = tid & 63, wv = tid >> 6, quad = lane >> 4, l15 = lane & 15;
  const int d = wv * 16 + l15;
  short8 b1h[2], b1l[2], b2h[2], b2l[2];
  #pragma unroll
  for (int ks = 0; ks < 2; ++ks) {
    load_split8(aa_w1 + d * 64 + quad * 8 + ks * 32, b1h[ks], b1l[ks]);
    load_split8(aa_w2 + d * 64 + quad * 8 + ks * 32, b2h[ks], b2l[ks]);
  }
  __syncthreads();
  int pp = 0;
  for (int t = blockIdx.x; t < N_USER / 16; t += gridDim.x) {
    int m0 = t * 16, arow = m0 + l15;
    const int erow = m0 + wv * 4 + quad;
    float4 ev0 = *(const float4*)(x0 + erow * 64 + l15 * 4);
    float4 ev1 = *(const float4*)(x1 + erow * 64 + l15 * 4);
    short8 ahh[2], ahl[2], a0h[2], a0l[2], a1h[2], a1l[2];
    #pragma unroll
    for (int ks = 0; ks < 2; ++ks) {
      load_split8(h  + arow * 64 + quad * 8 + ks * 32, ahh[ks], ahl[ks]);
      load_split8(x0 + arow * 64 + quad * 8 + ks * 32, a0h[ks], a0l[ks]);
      load_split8(x1 + arow * 64 + quad * 8 + ks * 32, a1h[ks], a1l[ks]);
    }
    floatx4 t1a = {0.f,0.f,0.f,0.f}, t20a = {0.f,0.f,0.f,0.f}, t21a = {0.f,0.f,0.f,0.f};
    #pragma unroll
    for (int ks = 0; ks < 2; ++ks) {
      t1a  = __builtin_amdgcn_mfma_f32_16x16x32_bf16(ahh[ks], b1h[ks], t1a, 0, 0, 0);
      t1a  = __builtin_amdgcn_mfma_f32_16x16x32_bf16(ahh[ks], b1l[ks], t1a, 0, 0, 0);
      t1a  = __builtin_amdgcn_mfma_f32_16x16x32_bf16(ahl[ks], b1h[ks], t1a, 0, 0, 0);
      t20a = __builtin_amdgcn_mfma_f32_16x16x32_bf16(a0h[ks], b2h[ks], t20a, 0, 0, 0);
      t20a = __builtin_amdgcn_mfma_f32_16x16x32_bf16(a0h[ks], b2l[ks], t20a, 0, 0, 0);
      t20a = __builtin_amdgcn_mfma_f32_16x16x32_bf16(a0l[ks], b2h[ks], t20a, 0, 0, 0);
      t21a = __builtin_amdgcn_mfma_f32_16x16x32_bf16(a1h[ks], b2h[ks], t21a, 0, 0, 0);
      t21a = __builtin_amdgcn_mfma_f32_16x16x32_bf16(a1h[ks], b2l[ks], t21a, 0, 0, 0);
      t21a = __builtin_amdgcn_mfma_f32_16x16x32_bf16(a1l[ks], b2h[ks], t21a, 0, 0, 0);
    }
    float am = aam_s[d];
    #pragma unroll
    for (int r = 0; r < 4; ++r) {
      float q0 = fast_tanh(t1a[r] + t20a[r]);
      float q1 = fast_tanh(t1a[r] + t21a[r]);
      float p0 = q0 * am, p1 = q1 * am;
      #pragma unroll
      for (int m = 1; m < 16; m <<= 1) { p0 += __shfl_xor(p0, m, 64); p1 += __shfl_xor(p1, m, 64); }
      if (l15 == 0) { scw0[pp][wv][quad * 4 + r] = p0; scw1[pp][wv][quad * 4 + r] = p1; }
    }
    __syncthreads();
    {
      int row = wv * 4 + quad, n = m0 + row;
      float s0 = scw0[pp][0][row] + scw0[pp][1][row] + scw0[pp][2][row] + scw0[pp][3][row];
      float s1 = scw1[pp][0][row] + scw1[pp][1][row] + scw1[pp][2][row] + scw1[pp][3][row];
      float mx = fmaxf(s0, s1);
      float e0 = __expf(s0 - mx), e1 = __expf(s1 - mx);
      float inv = 1.f / (e0 + e1);
      float b0 = e0 * inv, b1 = e1 * inv;
      float a0[4] = {ev0.x, ev0.y, ev0.z, ev0.w};
      float a1[4] = {ev1.x, ev1.y, ev1.z, ev1.w};
      float pc0 = 0.f, pc1 = 0.f;
      #pragma unroll
      for (int c = 0; c < 4; ++c) {
        int o = l15 * 4 + c;
        float fv = b0 * a0[c] + b1 * a1[c];
        pc0 += fcw_s[o] * a0[c] + fcw_s[64 + o] * a1[c] + fcw_s[128 + o] * fv;
        pc1 += fcw_s[192 + o] * a0[c] + fcw_s[256 + o] * a1[c] + fcw_s[320 + o] * fv;
      }
      #pragma unroll
      for (int m = 1; m < 16; m <<= 1) { pc0 += __shfl_xor(pc0, m, 64); pc1 += __shfl_xor(pc1, m, 64); }
      if (l15 == 0) {
        float l0 = pc0 + fcb_s[0], l1 = pc1 + fcb_s[1];
        float lm = fmaxf(l0, l1);
        float lse = lm + logf(__expf(l0 - lm) + __expf(l1 - lm));
        out[n * 2] = l0 - lse;
        out[n * 2 + 1] = l1 - lse;
      }
    }
    pp ^= 1;
  }
}

extern "C" void kernel_launch(void* const* d_in, const int* in_sizes, int n_in,
                              void* d_out, int out_size, void* d_ws, size_t ws_size,
                              hipStream_t stream)
{
  const float* h     = (const float*)d_in[0];
  const int*   src0  = (const int*)d_in[1];
  const int*   trg0  = (const int*)d_in[2];
  const int*   src1  = (const int*)d_in[3];
  const int*   trg1  = (const int*)d_in[4];
  const float* w0    = (const float*)d_in[5];
  const float* asrc0 = (const float*)d_in[6];
  const float* atrg0 = (const float*)d_in[7];
  const float* w1    = (const float*)d_in[8];
  const float* asrc1 = (const float*)d_in[9];
  const float* atrg1 = (const float*)d_in[10];
  const float* aa_w1 = (const float*)d_in[11];
  const float* aa_w2 = (const float*)d_in[12];
  const float* aa_m  = (const float*)d_in[13];
  const float* fc_w  = (const float*)d_in[14];
  const float* fc_b  = (const float*)d_in[15];
  float* out = (float*)d_out;

  // both-layers-resident needs ~155 MB (packed pairbuf); fall back if ws is tight
  const int nl = (ws_size >= (size_t)162 * 1024 * 1024) ? 2 : 1;
  const size_t L = (size_t)(nl - 1);   // 1 in concurrent mode, 0 in fallback

  char* ws = (char*)d_ws;
  size_t off = 0;
  auto alloc = [&](size_t bytes) -> void* {
    void* p = ws + off;
    off = (off + bytes + 255) & ~(size_t)255;
    return p;
  };
  uint*   hpi      = (uint*)alloc((size_t)nl * N_NODES * 64 * 4);
  float*  attn_src = (float*)alloc((size_t)nl * N_NODES * 2 * 4);
  float*  attn_trg = (float*)alloc((size_t)nl * N_NODES * 2 * 4);
  float*  x0       = (float*)alloc((size_t)N_USER * 64 * 4);
  float*  x1       = (float*)alloc((size_t)N_USER * 64 * 4);
  int*    offs     = (int*)alloc((size_t)nl * (N_USER + 1) * 4);
  int*    csr      = (int*)alloc((size_t)nl * N_EDGES * 4);
  uint*   pairbuf  = (uint*)alloc((size_t)nl * N_EDGES * 4);    // packed 4B entries
  float2* wgt      = (float2*)alloc((size_t)nl * N_EDGES * 8);
  int*    bhist    = (int*)alloc((size_t)2 * NBUCK * 4);
  int*    bstart   = (int*)alloc((size_t)2 * (NBUCK + 1) * 4);
  int*    bcur     = (int*)alloc((size_t)2 * NBUCK * 16 * 4);

  uint*   hpi1     = hpi + L * (size_t)N_NODES * 64;
  float*  attns1   = attn_src + L * (size_t)N_NODES * 2;
  float*  attnt1   = attn_trg + L * (size_t)N_NODES * 2;
  int*    offs1    = offs + L * (size_t)(N_USER + 1);
  int*    csr1     = csr + L * (size_t)N_EDGES;
  uint*   pairbuf1 = pairbuf + L * (size_t)N_EDGES;
  float2* wgt1     = wgt + L * (size_t)N_EDGES;

  if (nl == 2) {
    hipMemsetAsync(bhist, 0, (size_t)2 * NBUCK * 4, stream);
    hipLaunchKernelGGL(stage1, dim3(2 * HPB + 2 * TBLK), dim3(256), 0, stream,
                       h, w0, w1, asrc0, asrc1, atrg0, atrg1,
                       hpi, hpi1, attn_src, attns1, attn_trg, attnt1,
                       trg0, trg1, bhist, 2 * HPB, HPB, TBLK);
    hipLaunchKernelGGL(scanb2, dim3(2), dim3(256), 0, stream, bhist, bstart, bcur);
    hipLaunchKernelGGL(bucket2, dim3(2 * TBLK), dim3(256), 0, stream,
                       src0, src1, trg0, trg1, bcur, pairbuf, pairbuf1, TBLK);
    hipLaunchKernelGGL(fine2, dim3(2 * NBUCK), dim3(1024), 0, stream,
                       pairbuf, pairbuf1, bstart, offs, offs1, csr, csr1,
                       attn_src, attns1, attn_trg, attnt1, wgt, wgt1, NBUCK);
    hipLaunchKernelGGL(accfin, dim3(N_USER / 16), dim3(256), 0, stream,
                       offs, offs1, csr, csr1, wgt, wgt1, hpi, hpi1,
                       h, aa_w1, aa_w2, aa_m, fc_w, fc_b, out);
  } else {
    for (int layer = 0; layer < 2; ++layer) {
      const float* w    = layer ? w1 : w0;
      const float* asrc = layer ? asrc1 : asrc0;
      const float* atrg = layer ? atrg1 : atrg0;
      const int*   src  = layer ? src1 : src0;
      const int*   trg  = layer ? trg1 : trg0;
      float*       x    = layer ? x1 : x0;
      hipMemsetAsync(bhist, 0, (size_t)NBUCK * 4, stream);
      hipLaunchKernelGGL(stage1, dim3(HPB + TBLK), dim3(256), 0, stream,
                         h, w, w, asrc, asrc, atrg, atrg,
                         hpi, hpi, attn_src, attn_src, attn_trg, attn_trg,
                         trg, trg, bhist, HPB, HPB, TBLK);
      hipLaunchKernelGGL(scanb2, dim3(1), dim3(256), 0, stream, bhist, bstart, bcur);
      hipLaunchKernelGGL(bucket2, dim3(TBLK), dim3(256), 0, stream,
                         src, src, trg, trg, bcur, pairbuf, pairbuf, TBLK);
      hipLaunchKernelGGL(fine2, dim3(NBUCK), dim3(1024), 0, stream,
                         pairbuf, pairbuf, bstart, offs, offs, csr, csr,
                         attn_src, attn_src, attn_trg, attn_trg, wgt, wgt, NBUCK);
      hipLaunchKernelGGL(accum2, dim3(ACCB), dim3(256), 0, stream,
                         offs, offs, csr, csr, wgt, wgt, hpi, hpi, x, x, ACCB, 0);
    }
    hipLaunchKernelGGL(final_mfma, dim3(1875), dim3(256), 0, stream,
                       h, x0, x1, aa_w1, aa_w2, aa_m, fc_w, fc_b, out);
  }
}

// Round 14
// 425.644 us; speedup vs baseline: 1.0115x; 1.0115x over previous
//
#include <hip/hip_runtime.h>
#include <hip/hip_bf16.h>
#include <math.h>

#define N_NODES 100000
#define N_EDGES 1600000
#define N_USER  90000
#define NBUCK   256
#define BSZ     352   // targets per bucket; 256*352 = 90112 >= N_USER
#define TILE    2048  // edges per bucket/bhist block
#define TBLK    782   // (N_EDGES + TILE - 1) / TILE
#define ACCB    22500 // N_USER / 4
#define HPB     1024  // hp base grid (per layer)

typedef __attribute__((ext_vector_type(8))) short  short8;   // 8 bf16 (4 VGPRs) MFMA A/B frag
typedef __attribute__((ext_vector_type(4))) float  floatx4;  // MFMA C/D frag
typedef unsigned int  uint;
typedef unsigned short ushort;

__device__ __forceinline__ ushort f2bf(float x) {            // RNE fp32 -> bf16
  uint u = __float_as_uint(x);
  u += 0x7fffu + ((u >> 16) & 1u);
  return (ushort)(u >> 16);
}
__device__ __forceinline__ float bf2f(ushort v) { return __uint_as_float(((uint)v) << 16); }

__device__ __forceinline__ void split8(const float v[8], short8& hi, short8& lo) {
  #pragma unroll
  for (int j = 0; j < 8; ++j) {
    ushort h = f2bf(v[j]);
    hi[j] = (short)h;
    lo[j] = (short)f2bf(v[j] - bf2f(h));
  }
}
__device__ __forceinline__ void load_split8(const float* p, short8& hi, short8& lo) {
  const float4* q = (const float4*)p;
  float4 a = q[0], b = q[1];
  float v[8] = {a.x, a.y, a.z, a.w, b.x, b.y, b.z, b.w};
  split8(v, hi, lo);
}
__device__ __forceinline__ float fast_tanh(float x) {
  float t = __expf(2.f * x);
  return 1.f - 2.f / (t + 1.f);
}

// ---------------- stage1: hp (MFMA) for both layers  ||  bhist for both layers ----------
__global__ __launch_bounds__(256) void stage1(
    const float* __restrict__ h,
    const float* __restrict__ wA,  const float* __restrict__ wB,
    const float* __restrict__ asA, const float* __restrict__ asB,
    const float* __restrict__ atA, const float* __restrict__ atB,
    uint* __restrict__ hpiA, uint* __restrict__ hpiB,
    float* __restrict__ attnsA, float* __restrict__ attnsB,
    float* __restrict__ attntA, float* __restrict__ attntB,
    const int* __restrict__ trgA, const int* __restrict__ trgB,
    int* __restrict__ bhist,
    int hpTot, int hpBase, int bhBase)
{
  __shared__ float part[4][16][4];          // hp: [wave][row][as0,as1,at0,at1]
  __shared__ int hh[NBUCK];                 // bhist
  const int tid = threadIdx.x;

  if (blockIdx.x >= hpTot) {                // ---- bhist branch ----
    const int b2 = blockIdx.x - hpTot;
    const int layer = (b2 >= bhBase) ? 1 : 0;
    const int bid = b2 - layer * bhBase;
    const int* trg = layer ? trgB : trgA;
    int* bh = bhist + layer * NBUCK;
    hh[tid] = 0;
    __syncthreads();
    const int b0 = bid * TILE;
    #pragma unroll
    for (int j = 0; j < 8; ++j) {
      int e = b0 + j * 256 + tid;
      if (e < N_EDGES) {
        int t = trg[e];
        if (t < N_USER) atomicAdd(&hh[t / BSZ], 1);
      }
    }
    __syncthreads();
    if (hh[tid]) atomicAdd(&bh[tid], hh[tid]);
    return;
  }

  // ---- hp branch ----
  const int layer = (blockIdx.x >= hpBase) ? 1 : 0;
  const int bid = blockIdx.x - layer * hpBase;
  const float* w     = layer ? wB : wA;
  const float* a_src = layer ? asB : asA;
  const float* a_trg = layer ? atB : atA;
  uint*  hpi      = layer ? hpiB : hpiA;
  float* attn_src = layer ? attnsB : attnsA;
  float* attn_trg = layer ? attntB : attntA;

  const int lane = tid & 63, wv = tid >> 6;
  const int quad = lane >> 4, l15 = lane & 15;
  const int o = wv * 16 + l15;              // wave's 16-col slice of the 64 outputs
  const float vas0 = a_src[o], vas1 = a_src[64 + o];
  const float vat0 = a_trg[o], vat1 = a_trg[64 + o];
  short8 b0h[2], b0l[2], b1h[2], b1l[2];    // B frags: head0/head1 x ksteps
  #pragma unroll
  for (int ks = 0; ks < 2; ++ks) {
    float v0[8], v1[8];
    #pragma unroll
    for (int j = 0; j < 8; ++j) {
      int k = quad * 8 + j + ks * 32;       // f index
      v0[j] = w[k * 64 + o];                // w[0][f][o]
      v1[j] = w[4096 + k * 64 + o];         // w[1][f][o]
    }
    split8(v0, b0h[ks], b0l[ks]);
    split8(v1, b1h[ks], b1l[ks]);
  }
  for (int t = bid; t < N_NODES / 16; t += hpBase) {
    int m0 = t * 16, arow = m0 + l15;
    short8 ah[2], al[2];
    #pragma unroll
    for (int ks = 0; ks < 2; ++ks)
      load_split8(h + arow * 64 + quad * 8 + ks * 32, ah[ks], al[ks]);
    floatx4 c0 = {0.f, 0.f, 0.f, 0.f}, c1 = {0.f, 0.f, 0.f, 0.f};
    #pragma unroll
    for (int ks = 0; ks < 2; ++ks) {
      c0 = __builtin_amdgcn_mfma_f32_16x16x32_bf16(ah[ks], b0h[ks], c0, 0, 0, 0);
      c0 = __builtin_amdgcn_mfma_f32_16x16x32_bf16(ah[ks], b0l[ks], c0, 0, 0, 0);
      c0 = __builtin_amdgcn_mfma_f32_16x16x32_bf16(al[ks], b0h[ks], c0, 0, 0, 0);
      c1 = __builtin_amdgcn_mfma_f32_16x16x32_bf16(ah[ks], b1h[ks], c1, 0, 0, 0);
      c1 = __builtin_amdgcn_mfma_f32_16x16x32_bf16(ah[ks], b1l[ks], c1, 0, 0, 0);
      c1 = __builtin_amdgcn_mfma_f32_16x16x32_bf16(al[ks], b1h[ks], c1, 0, 0, 0);
    }
    #pragma unroll
    for (int r = 0; r < 4; ++r) {
      int n = m0 + quad * 4 + r;
      hpi[n * 64 + o] = (uint)f2bf(c0[r]) | ((uint)f2bf(c1[r]) << 16);
    }
    #pragma unroll
    for (int r = 0; r < 4; ++r) {
      float pas0 = c0[r] * vas0, pas1 = c1[r] * vas1;
      float pat0 = c0[r] * vat0, pat1 = c1[r] * vat1;
      #pragma unroll
      for (int m = 1; m < 16; m <<= 1) {
        pas0 += __shfl_xor(pas0, m, 64); pas1 += __shfl_xor(pas1, m, 64);
        pat0 += __shfl_xor(pat0, m, 64); pat1 += __shfl_xor(pat1, m, 64);
      }
      if (l15 == 0) {
        part[wv][quad * 4 + r][0] = pas0; part[wv][quad * 4 + r][1] = pas1;
        part[wv][quad * 4 + r][2] = pat0; part[wv][quad * 4 + r][3] = pat1;
      }
    }
    __syncthreads();
    if (tid < 64) {
      int row = tid & 15, which = tid >> 4;
      float v = part[0][row][which] + part[1][row][which]
              + part[2][row][which] + part[3][row][which];
      int n = m0 + row;
      if (which == 0)      attn_src[n * 2]     = v;
      else if (which == 1) attn_src[n * 2 + 1] = v;
      else if (which == 2) attn_trg[n * 2]     = v;
      else                 attn_trg[n * 2 + 1] = v;
    }
    __syncthreads();
  }
}

// 1-block-per-layer scan of the 256 bucket sizes -> bstart[257] + seeded bucket cursors.
__global__ __launch_bounds__(256) void scanb2(const int* __restrict__ bhist,
                                              int* __restrict__ bstart, int* __restrict__ bcur)
{
  const int layer = blockIdx.x;
  const int* bh = bhist + layer * NBUCK;
  int* bs = bstart + layer * (NBUCK + 1);
  int* bc = bcur + layer * NBUCK * 16;
  __shared__ int s[256];
  int v = bh[threadIdx.x];
  s[threadIdx.x] = v;
  __syncthreads();
  for (int d = 1; d < 256; d <<= 1) {
    int t = (threadIdx.x >= d) ? s[threadIdx.x - d] : 0;
    __syncthreads();
    s[threadIdx.x] += t;
    __syncthreads();
  }
  int excl = s[threadIdx.x] - v;
  bs[threadIdx.x] = excl;
  bc[threadIdx.x * 16] = excl;
  if (threadIdx.x == 255) bs[256] = s[255];
}

// Pass B: bin a 2048-edge tile by bucket in LDS, bulk-append contiguous runs per bucket.
// Packed pairbuf: src (17b) | bucket-local trg (9b); bucket id rides in LDS.
__global__ __launch_bounds__(256) void bucket2(
    const int* __restrict__ srcA, const int* __restrict__ srcB,
    const int* __restrict__ trgA, const int* __restrict__ trgB,
    int* __restrict__ bcur, uint* __restrict__ pairbufA, uint* __restrict__ pairbufB, int base)
{
  const int layer = (blockIdx.x >= base) ? 1 : 0;
  const int bid = blockIdx.x - layer * base;
  const int* src = layer ? srcB : srcA;
  const int* trg = layer ? trgB : trgA;
  int* bc = bcur + layer * NBUCK * 16;
  uint* pairbuf = layer ? pairbufB : pairbufA;

  __shared__ uint2 plds[TILE];              // (packed entry, bucket id)
  __shared__ int bcnt[NBUCK], bscan[NBUCK], gbase[NBUCK];
  const int tid = threadIdx.x;
  const int b0 = bid * TILE;
  bcnt[tid] = 0;
  __syncthreads();
  int myb[8], myr[8];
  uint myp[8];
  #pragma unroll
  for (int j = 0; j < 8; ++j) {
    int e = b0 + j * 256 + tid;
    myb[j] = -1;
    if (e < N_EDGES) {
      int t = trg[e];
      if (t < N_USER) {
        int b = t / BSZ;
        int tl = t - b * BSZ;               // < 352, fits 9 bits
        myb[j] = b;
        myr[j] = atomicAdd(&bcnt[b], 1);
        myp[j] = (uint)src[e] | ((uint)tl << 17);   // src < 2^17
      }
    }
  }
  __syncthreads();
  gbase[tid] = atomicAdd(&bc[tid * 16], bcnt[tid]);
  bscan[tid] = bcnt[tid];
  __syncthreads();
  for (int d = 1; d < 256; d <<= 1) {
    int v = (tid >= d) ? bscan[tid - d] : 0;
    __syncthreads();
    bscan[tid] += v;
    __syncthreads();
  }
  #pragma unroll
  for (int j = 0; j < 8; ++j)
    if (myb[j] >= 0) plds[bscan[myb[j]] - bcnt[myb[j]] + myr[j]] = make_uint2(myp[j], (uint)myb[j]);
  __syncthreads();
  int total = bscan[NBUCK - 1];
  for (int i = tid; i < total; i += 256) {
    uint2 pr = plds[i];
    int b = (int)pr.y;
    int idx = gbase[b] + (i - (bscan[b] - bcnt[b]));
    if (idx >= 0 && idx < N_EDGES) pairbuf[idx] = pr.x;
  }
}

// Pass C: one block per bucket (x2 layers), 1024 threads. Per-target offs in LDS.
__global__ __launch_bounds__(1024) void fine2(
    const uint* __restrict__ pairbufA, const uint* __restrict__ pairbufB,
    const int* __restrict__ bstart,
    int* __restrict__ offsA, int* __restrict__ offsB,
    int* __restrict__ csrA,  int* __restrict__ csrB,
    const float* __restrict__ attnsA, const float* __restrict__ attnsB,
    const float* __restrict__ attntA, const float* __restrict__ attntB,
    float2* __restrict__ wgtA, float2* __restrict__ wgtB, int base)
{
  const int layer = (blockIdx.x >= base) ? 1 : 0;
  const int b = blockIdx.x - layer * base;
  const uint* pairbuf = layer ? pairbufB : pairbufA;
  const int* bs = bstart + layer * (NBUCK + 1);
  int* offs = layer ? offsB : offsA;
  int* csr_src = layer ? csrB : csrA;
  const float* attn_src = layer ? attnsB : attnsA;
  const float* attn_trg = layer ? attntB : attntA;
  float2* wgt = layer ? wgtB : wgtA;

  __shared__ int cnt[BSZ + 1];
  __shared__ int cur[BSZ];
  const int tid = threadIdx.x;
  const int t0 = b * BSZ;
  const int nt = min(BSZ, N_USER - t0);     // 240 for bucket 255
  const int pbeg = bs[b], pend = bs[b + 1];
  for (int j = tid; j <= BSZ; j += 1024) cnt[j] = 0;
  __syncthreads();
  for (int i = pbeg + tid; i < pend; i += 1024) {
    int tl = min((int)(pairbuf[i] >> 17), BSZ - 1);
    atomicAdd(&cnt[tl], 1);
  }
  __syncthreads();
  if (tid == 0) {                           // serial exclusive scan, <=352 elems
    int run = 0;
    for (int j = 0; j < nt; ++j) { int c = cnt[j]; cnt[j] = run; run += c; }
    cnt[nt] = run;
  }
  __syncthreads();
  for (int j = tid; j < nt; j += 1024) {
    offs[t0 + j] = pbeg + cnt[j];
    cur[j] = cnt[j];
  }
  if (tid == 0 && t0 + nt == N_USER) offs[N_USER] = pbeg + cnt[nt];
  __syncthreads();
  const float2* as2 = (const float2*)attn_src;
  const float2* at2 = (const float2*)attn_trg;
  for (int i = pbeg + tid; i < pend; i += 1024) {
    uint v = pairbuf[i];
    int s = min((int)(v & 0x1FFFFu), N_NODES - 1);
    int tl = min((int)(v >> 17), BSZ - 1);
    int tt = min(t0 + tl, N_USER - 1);
    float2 as = as2[s];
    float2 at = at2[tt];
    float e0 = as.x + at.x; e0 = (e0 > 0.f) ? e0 : 0.2f * e0;
    float e1 = as.y + at.y; e1 = (e1 > 0.f) ? e1 : 0.2f * e1;
    int p = pbeg + atomicAdd(&cur[tl], 1);
    p = min(max(p, 0), N_EDGES - 1);
    csr_src[p] = s;
    wgt[p] = make_float2(__expf(e0), __expf(e1));
  }
}

// ---------------- per-target accumulation (R9-verbatim: scalarized + XCD affinity) ------
__global__ __launch_bounds__(256) void accum2(
    const int* __restrict__ offsA, const int* __restrict__ offsB,
    const int* __restrict__ csrA,  const int* __restrict__ csrB,
    const float2* __restrict__ wgtA, const float2* __restrict__ wgtB,
    const uint* __restrict__ hpiA, const uint* __restrict__ hpiB,
    float* __restrict__ xA, float* __restrict__ xB, int base, int swz)
{
  int layer, bid;
  if (swz) {
    const int xcd = blockIdx.x & 7, idx = blockIdx.x >> 3;
    layer = xcd >> 2;
    bid = idx * 4 + (xcd & 3);
  } else {
    layer = (blockIdx.x >= base) ? 1 : 0;
    bid = blockIdx.x - layer * base;
  }
  const int* offs = layer ? offsB : offsA;
  const int* csr_src = layer ? csrB : csrA;
  const float2* wgt = layer ? wgtB : wgtA;
  const uint* hpi = layer ? hpiB : hpiA;
  float* x = layer ? xB : xA;

  const int lane = threadIdx.x & 63, wv = threadIdx.x >> 6;
  int n = bid * 4 + wv;
  if (n >= N_USER) return;
  int beg = max(0, offs[n]);
  int end = min(offs[n + 1], N_EDGES);
  beg = __builtin_amdgcn_readfirstlane(beg);   // wave-uniform by construction
  end = __builtin_amdgcn_readfirstlane(end);
  int deg = end - beg;
  float acc0 = 0.f, acc1 = 0.f, den0 = 0.f, den1 = 0.f;
  for (int base2 = 0; base2 < deg; base2 += 64) {
    int rem = min(64, deg - base2);
    int sv = csr_src[beg + base2 + min(lane, rem - 1)];  // coalesced; lanes>=rem dup last
    sv = min(max(sv, 0), N_NODES - 1);                   // clamp once, pre-broadcast
    int nfull = rem & ~7;
    for (int j = 0; j < nfull; j += 8) {                 // lean full blocks
      int ss[8]; uint pv[8]; float2 W[8];
      #pragma unroll
      for (int u = 0; u < 8; ++u) ss[u] = __builtin_amdgcn_readlane(sv, j + u);  // SGPR
      #pragma unroll
      for (int u = 0; u < 8; ++u) pv[u] = (hpi + (size_t)ss[u] * 64)[lane];      // saddr
      #pragma unroll
      for (int u = 0; u < 8; ++u) W[u] = wgt[beg + base2 + j + u];               // s_load
      #pragma unroll
      for (int u = 0; u < 8; ++u) {
        den0 += W[u].x; den1 += W[u].y;
        acc0 += W[u].x * bf2f((ushort)(pv[u] & 0xffffu));
        acc1 += W[u].y * bf2f((ushort)(pv[u] >> 16));
      }
    }
    if (nfull < rem) {                                   // single masked tail block
      int j = nfull;
      int ss[8]; uint pv[8]; float2 W[8];
      #pragma unroll
      for (int u = 0; u < 8; ++u) ss[u] = __builtin_amdgcn_readlane(sv, min(j + u, rem - 1));
      #pragma unroll
      for (int u = 0; u < 8; ++u) pv[u] = (hpi + (size_t)ss[u] * 64)[lane];
      #pragma unroll
      for (int u = 0; u < 8; ++u)
        W[u] = (j + u < rem) ? wgt[beg + base2 + j + u] : make_float2(0.f, 0.f);
      #pragma unroll
      for (int u = 0; u < 8; ++u) {
        den0 += W[u].x; den1 += W[u].y;
        acc0 += W[u].x * bf2f((ushort)(pv[u] & 0xffffu));
        acc1 += W[u].y * bf2f((ushort)(pv[u] >> 16));
      }
    }
  }
  x[n * 64 + lane] = 0.5f * (acc0 / (den0 + 1e-16f) + acc1 / (den1 + 1e-16f));
}

// ---------------- final: 3 MFMA GEMMs + fused epilogue ----------------
// scw double-buffered (ping-pong per tile) -> only ONE barrier per tile instead of
// two. Iteration t+1 writes the other buffer; its barrier transitively orders reuse of
// buffer pp (all waves passed t+1's barrier => all finished t's reads). Results identical.
__global__ __launch_bounds__(256) void final_mfma(
    const float* __restrict__ h, const float* __restrict__ x0, const float* __restrict__ x1,
    const float* __restrict__ aa_w1, const float* __restrict__ aa_w2, const float* __restrict__ aa_m,
    const float* __restrict__ fc_w, const float* __restrict__ fc_b, float* __restrict__ out)
{
  __shared__ float aam_s[64], fcw_s[384], fcb_s[2];
  __shared__ float scw0[2][4][16], scw1[2][4][16];
  const int tid = threadIdx.x;
  if (tid < 64)  aam_s[tid] = aa_m[tid];
  for (int i = tid; i < 384; i += 256) fcw_s[i] = fc_w[i];
  if (tid < 2)   fcb_s[tid] = fc_b[tid];
  const int lane = tid & 63, wv = tid >> 6, quad = lane >> 4, l15 = lane & 15;
  const int d = wv * 16 + l15;
  short8 b1h[2], b1l[2], b2h[2], b2l[2];
  #pragma unroll
  for (int ks = 0; ks < 2; ++ks) {
    load_split8(aa_w1 + d * 64 + quad * 8 + ks * 32, b1h[ks], b1l[ks]);
    load_split8(aa_w2 + d * 64 + quad * 8 + ks * 32, b2h[ks], b2l[ks]);
  }
  __syncthreads();
  int pp = 0;
  for (int t = blockIdx.x; t < N_USER / 16; t += gridDim.x) {
    int m0 = t * 16, arow = m0 + l15;
    const int erow = m0 + wv * 4 + quad;
    float4 ev0 = *(const float4*)(x0 + erow * 64 + l15 * 4);
    float4 ev1 = *(const float4*)(x1 + erow * 64 + l15 * 4);
    short8 ahh[2], ahl[2], a0h[2], a0l[2], a1h[2], a1l[2];
    #pragma unroll
    for (int ks = 0; ks < 2; ++ks) {
      load_split8(h  + arow * 64 + quad * 8 + ks * 32, ahh[ks], ahl[ks]);
      load_split8(x0 + arow * 64 + quad * 8 + ks * 32, a0h[ks], a0l[ks]);
      load_split8(x1 + arow * 64 + quad * 8 + ks * 32, a1h[ks], a1l[ks]);
    }
    floatx4 t1a = {0.f,0.f,0.f,0.f}, t20a = {0.f,0.f,0.f,0.f}, t21a = {0.f,0.f,0.f,0.f};
    #pragma unroll
    for (int ks = 0; ks < 2; ++ks) {
      t1a  = __builtin_amdgcn_mfma_f32_16x16x32_bf16(ahh[ks], b1h[ks], t1a, 0, 0, 0);
      t1a  = __builtin_amdgcn_mfma_f32_16x16x32_bf16(ahh[ks], b1l[ks], t1a, 0, 0, 0);
      t1a  = __builtin_amdgcn_mfma_f32_16x16x32_bf16(ahl[ks], b1h[ks], t1a, 0, 0, 0);
      t20a = __builtin_amdgcn_mfma_f32_16x16x32_bf16(a0h[ks], b2h[ks], t20a, 0, 0, 0);
      t20a = __builtin_amdgcn_mfma_f32_16x16x32_bf16(a0h[ks], b2l[ks], t20a, 0, 0, 0);
      t20a = __builtin_amdgcn_mfma_f32_16x16x32_bf16(a0l[ks], b2h[ks], t20a, 0, 0, 0);
      t21a = __builtin_amdgcn_mfma_f32_16x16x32_bf16(a1h[ks], b2h[ks], t21a, 0, 0, 0);
      t21a = __builtin_amdgcn_mfma_f32_16x16x32_bf16(a1h[ks], b2l[ks], t21a, 0, 0, 0);
      t21a = __builtin_amdgcn_mfma_f32_16x16x32_bf16(a1l[ks], b2h[ks], t21a, 0, 0, 0);
    }
    float am = aam_s[d];
    #pragma unroll
    for (int r = 0; r < 4; ++r) {
      float q0 = fast_tanh(t1a[r] + t20a[r]);
      float q1 = fast_tanh(t1a[r] + t21a[r]);
      float p0 = q0 * am, p1 = q1 * am;
      #pragma unroll
      for (int m = 1; m < 16; m <<= 1) { p0 += __shfl_xor(p0, m, 64); p1 += __shfl_xor(p1, m, 64); }
      if (l15 == 0) { scw0[pp][wv][quad * 4 + r] = p0; scw1[pp][wv][quad * 4 + r] = p1; }
    }
    __syncthreads();
    {
      int row = wv * 4 + quad, n = m0 + row;
      float s0 = scw0[pp][0][row] + scw0[pp][1][row] + scw0[pp][2][row] + scw0[pp][3][row];
      float s1 = scw1[pp][0][row] + scw1[pp][1][row] + scw1[pp][2][row] + scw1[pp][3][row];
      float mx = fmaxf(s0, s1);
      float e0 = __expf(s0 - mx), e1 = __expf(s1 - mx);
      float inv = 1.f / (e0 + e1);
      float b0 = e0 * inv, b1 = e1 * inv;
      float a0[4] = {ev0.x, ev0.y, ev0.z, ev0.w};
      float a1[4] = {ev1.x, ev1.y, ev1.z, ev1.w};
      float pc0 = 0.f, pc1 = 0.f;
      #pragma unroll
      for (int c = 0; c < 4; ++c) {
        int o = l15 * 4 + c;
        float fv = b0 * a0[c] + b1 * a1[c];
        pc0 += fcw_s[o] * a0[c] + fcw_s[64 + o] * a1[c] + fcw_s[128 + o] * fv;
        pc1 += fcw_s[192 + o] * a0[c] + fcw_s[256 + o] * a1[c] + fcw_s[320 + o] * fv;
      }
      #pragma unroll
      for (int m = 1; m < 16; m <<= 1) { pc0 += __shfl_xor(pc0, m, 64); pc1 += __shfl_xor(pc1, m, 64); }
      if (l15 == 0) {
        float l0 = pc0 + fcb_s[0], l1 = pc1 + fcb_s[1];
        float lm = fmaxf(l0, l1);
        float lse = lm + logf(__expf(l0 - lm) + __expf(l1 - lm));
        out[n * 2] = l0 - lse;
        out[n * 2 + 1] = l1 - lse;
      }
    }
    pp ^= 1;                                // no trailing barrier: next tile writes other buffer
  }
}

extern "C" void kernel_launch(void* const* d_in, const int* in_sizes, int n_in,
                              void* d_out, int out_size, void* d_ws, size_t ws_size,
                              hipStream_t stream)
{
  const float* h     = (const float*)d_in[0];
  const int*   src0  = (const int*)d_in[1];
  const int*   trg0  = (const int*)d_in[2];
  const int*   src1  = (const int*)d_in[3];
  const int*   trg1  = (const int*)d_in[4];
  const float* w0    = (const float*)d_in[5];
  const float* asrc0 = (const float*)d_in[6];
  const float* atrg0 = (const float*)d_in[7];
  const float* w1    = (const float*)d_in[8];
  const float* asrc1 = (const float*)d_in[9];
  const float* atrg1 = (const float*)d_in[10];
  const float* aa_w1 = (const float*)d_in[11];
  const float* aa_w2 = (const float*)d_in[12];
  const float* aa_m  = (const float*)d_in[13];
  const float* fc_w  = (const float*)d_in[14];
  const float* fc_b  = (const float*)d_in[15];
  float* out = (float*)d_out;

  // both-layers-resident needs ~155 MB (packed pairbuf); fall back if ws is tight
  const int nl = (ws_size >= (size_t)162 * 1024 * 1024) ? 2 : 1;
  const size_t L = (size_t)(nl - 1);   // 1 in concurrent mode, 0 in fallback

  char* ws = (char*)d_ws;
  size_t off = 0;
  auto alloc = [&](size_t bytes) -> void* {
    void* p = ws + off;
    off = (off + bytes + 255) & ~(size_t)255;
    return p;
  };
  uint*   hpi      = (uint*)alloc((size_t)nl * N_NODES * 64 * 4);
  float*  attn_src = (float*)alloc((size_t)nl * N_NODES * 2 * 4);
  float*  attn_trg = (float*)alloc((size_t)nl * N_NODES * 2 * 4);
  float*  x0       = (float*)alloc((size_t)N_USER * 64 * 4);
  float*  x1       = (float*)alloc((size_t)N_USER * 64 * 4);
  int*    offs     = (int*)alloc((size_t)nl * (N_USER + 1) * 4);
  int*    csr      = (int*)alloc((size_t)nl * N_EDGES * 4);
  uint*   pairbuf  = (uint*)alloc((size_t)nl * N_EDGES * 4);    // packed 4B entries
  float2* wgt      = (float2*)alloc((size_t)nl * N_EDGES * 8);
  int*    bhist    = (int*)alloc((size_t)2 * NBUCK * 4);
  int*    bstart   = (int*)alloc((size_t)2 * (NBUCK + 1) * 4);
  int*    bcur     = (int*)alloc((size_t)2 * NBUCK * 16 * 4);

  uint*   hpi1     = hpi + L * (size_t)N_NODES * 64;
  float*  attns1   = attn_src + L * (size_t)N_NODES * 2;
  float*  attnt1   = attn_trg + L * (size_t)N_NODES * 2;
  int*    offs1    = offs + L * (size_t)(N_USER + 1);
  int*    csr1     = csr + L * (size_t)N_EDGES;
  uint*   pairbuf1 = pairbuf + L * (size_t)N_EDGES;
  float2* wgt1     = wgt + L * (size_t)N_EDGES;

  if (nl == 2) {
    hipMemsetAsync(bhist, 0, (size_t)2 * NBUCK * 4, stream);
    hipLaunchKernelGGL(stage1, dim3(2 * HPB + 2 * TBLK), dim3(256), 0, stream,
                       h, w0, w1, asrc0, asrc1, atrg0, atrg1,
                       hpi, hpi1, attn_src, attns1, attn_trg, attnt1,
                       trg0, trg1, bhist, 2 * HPB, HPB, TBLK);
    hipLaunchKernelGGL(scanb2, dim3(2), dim3(256), 0, stream, bhist, bstart, bcur);
    hipLaunchKernelGGL(bucket2, dim3(2 * TBLK), dim3(256), 0, stream,
                       src0, src1, trg0, trg1, bcur, pairbuf, pairbuf1, TBLK);
    hipLaunchKernelGGL(fine2, dim3(2 * NBUCK), dim3(1024), 0, stream,
                       pairbuf, pairbuf1, bstart, offs, offs1, csr, csr1,
                       attn_src, attns1, attn_trg, attnt1, wgt, wgt1, NBUCK);
    hipLaunchKernelGGL(accum2, dim3(2 * ACCB), dim3(256), 0, stream,
                       offs, offs1, csr, csr1, wgt, wgt1, hpi, hpi1, x0, x1, ACCB, 1);
  } else {
    for (int layer = 0; layer < 2; ++layer) {
      const float* w    = layer ? w1 : w0;
      const float* asrc = layer ? asrc1 : asrc0;
      const float* atrg = layer ? atrg1 : atrg0;
      const int*   src  = layer ? src1 : src0;
      const int*   trg  = layer ? trg1 : trg0;
      float*       x    = layer ? x1 : x0;
      hipMemsetAsync(bhist, 0, (size_t)NBUCK * 4, stream);
      hipLaunchKernelGGL(stage1, dim3(HPB + TBLK), dim3(256), 0, stream,
                         h, w, w, asrc, asrc, atrg, atrg,
                         hpi, hpi, attn_src, attn_src, attn_trg, attn_trg,
                         trg, trg, bhist, HPB, HPB, TBLK);
      hipLaunchKernelGGL(scanb2, dim3(1), dim3(256), 0, stream, bhist, bstart, bcur);
      hipLaunchKernelGGL(bucket2, dim3(TBLK), dim3(256), 0, stream,
                         src, src, trg, trg, bcur, pairbuf, pairbuf, TBLK);
      hipLaunchKernelGGL(fine2, dim3(NBUCK), dim3(1024), 0, stream,
                         pairbuf, pairbuf, bstart, offs, offs, csr, csr,
                         attn_src, attn_src, attn_trg, attn_trg, wgt, wgt, NBUCK);
      hipLaunchKernelGGL(accum2, dim3(ACCB), dim3(256), 0, stream,
                         offs, offs, csr, csr, wgt, wgt, hpi, hpi, x, x, ACCB, 0);
    }
  }
  hipLaunchKernelGGL(final_mfma, dim3(1875), dim3(256), 0, stream,
                     h, x0, x1, aa_w1, aa_w2, aa_m, fc_w, fc_b, out);
}

// Round 15
// 422.804 us; speedup vs baseline: 1.0183x; 1.0067x over previous
//
#include <hip/hip_runtime.h>
#include <hip/hip_bf16.h>
#include <math.h>

#define N_NODES 100000
#define N_EDGES 1600000
#define N_USER  90000
#define NBUCK   256
#define BSZ     352   // targets per bucket; 256*352 = 90112 >= N_USER
#define TILE    2048  // edges per bucket/bhist block
#define TBLK    782   // (N_EDGES + TILE - 1) / TILE
#define ACCB    22500 // N_USER / 4
#define HPB     1024  // hp base grid (per layer)

typedef __attribute__((ext_vector_type(8))) short  short8;   // 8 bf16 (4 VGPRs) MFMA A/B frag
typedef __attribute__((ext_vector_type(4))) float  floatx4;  // MFMA C/D frag
typedef unsigned int  uint;
typedef unsigned short ushort;

__device__ __forceinline__ ushort f2bf(float x) {            // RNE fp32 -> bf16
  uint u = __float_as_uint(x);
  u += 0x7fffu + ((u >> 16) & 1u);
  return (ushort)(u >> 16);
}
__device__ __forceinline__ float bf2f(ushort v) { return __uint_as_float(((uint)v) << 16); }

__device__ __forceinline__ void split8(const float v[8], short8& hi, short8& lo) {
  #pragma unroll
  for (int j = 0; j < 8; ++j) {
    ushort h = f2bf(v[j]);
    hi[j] = (short)h;
    lo[j] = (short)f2bf(v[j] - bf2f(h));
  }
}
__device__ __forceinline__ void load_split8(const float* p, short8& hi, short8& lo) {
  const float4* q = (const float4*)p;
  float4 a = q[0], b = q[1];
  float v[8] = {a.x, a.y, a.z, a.w, b.x, b.y, b.z, b.w};
  split8(v, hi, lo);
}
__device__ __forceinline__ float fast_tanh(float x) {
  float t = __expf(2.f * x);
  return 1.f - 2.f / (t + 1.f);
}

// ---------------- stage1: hp (MFMA) for both layers  ||  bhist for both layers ----------
__global__ __launch_bounds__(256) void stage1(
    const float* __restrict__ h,
    const float* __restrict__ wA,  const float* __restrict__ wB,
    const float* __restrict__ asA, const float* __restrict__ asB,
    const float* __restrict__ atA, const float* __restrict__ atB,
    uint* __restrict__ hpiA, uint* __restrict__ hpiB,
    float* __restrict__ attnsA, float* __restrict__ attnsB,
    float* __restrict__ attntA, float* __restrict__ attntB,
    const int* __restrict__ trgA, const int* __restrict__ trgB,
    int* __restrict__ bhist,
    int hpTot, int hpBase, int bhBase)
{
  __shared__ float part[4][16][4];          // hp: [wave][row][as0,as1,at0,at1]
  __shared__ int hh[NBUCK];                 // bhist
  const int tid = threadIdx.x;

  if (blockIdx.x >= hpTot) {                // ---- bhist branch ----
    const int b2 = blockIdx.x - hpTot;
    const int layer = (b2 >= bhBase) ? 1 : 0;
    const int bid = b2 - layer * bhBase;
    const int* trg = layer ? trgB : trgA;
    int* bh = bhist + layer * NBUCK;
    hh[tid] = 0;
    __syncthreads();
    const int b0 = bid * TILE;
    #pragma unroll
    for (int j = 0; j < 8; ++j) {
      int e = b0 + j * 256 + tid;
      if (e < N_EDGES) {
        int t = trg[e];
        if (t < N_USER) atomicAdd(&hh[t / BSZ], 1);
      }
    }
    __syncthreads();
    if (hh[tid]) atomicAdd(&bh[tid], hh[tid]);
    return;
  }

  // ---- hp branch ----
  const int layer = (blockIdx.x >= hpBase) ? 1 : 0;
  const int bid = blockIdx.x - layer * hpBase;
  const float* w     = layer ? wB : wA;
  const float* a_src = layer ? asB : asA;
  const float* a_trg = layer ? atB : atA;
  uint*  hpi      = layer ? hpiB : hpiA;
  float* attn_src = layer ? attnsB : attnsA;
  float* attn_trg = layer ? attntB : attntA;

  const int lane = tid & 63, wv = tid >> 6;
  const int quad = lane >> 4, l15 = lane & 15;
  const int o = wv * 16 + l15;              // wave's 16-col slice of the 64 outputs
  const float vas0 = a_src[o], vas1 = a_src[64 + o];
  const float vat0 = a_trg[o], vat1 = a_trg[64 + o];
  short8 b0h[2], b0l[2], b1h[2], b1l[2];    // B frags: head0/head1 x ksteps
  #pragma unroll
  for (int ks = 0; ks < 2; ++ks) {
    float v0[8], v1[8];
    #pragma unroll
    for (int j = 0; j < 8; ++j) {
      int k = quad * 8 + j + ks * 32;       // f index
      v0[j] = w[k * 64 + o];                // w[0][f][o]
      v1[j] = w[4096 + k * 64 + o];         // w[1][f][o]
    }
    split8(v0, b0h[ks], b0l[ks]);
    split8(v1, b1h[ks], b1l[ks]);
  }
  for (int t = bid; t < N_NODES / 16; t += hpBase) {
    int m0 = t * 16, arow = m0 + l15;
    short8 ah[2], al[2];
    #pragma unroll
    for (int ks = 0; ks < 2; ++ks)
      load_split8(h + arow * 64 + quad * 8 + ks * 32, ah[ks], al[ks]);
    floatx4 c0 = {0.f, 0.f, 0.f, 0.f}, c1 = {0.f, 0.f, 0.f, 0.f};
    #pragma unroll
    for (int ks = 0; ks < 2; ++ks) {
      c0 = __builtin_amdgcn_mfma_f32_16x16x32_bf16(ah[ks], b0h[ks], c0, 0, 0, 0);
      c0 = __builtin_amdgcn_mfma_f32_16x16x32_bf16(ah[ks], b0l[ks], c0, 0, 0, 0);
      c0 = __builtin_amdgcn_mfma_f32_16x16x32_bf16(al[ks], b0h[ks], c0, 0, 0, 0);
      c1 = __builtin_amdgcn_mfma_f32_16x16x32_bf16(ah[ks], b1h[ks], c1, 0, 0, 0);
      c1 = __builtin_amdgcn_mfma_f32_16x16x32_bf16(ah[ks], b1l[ks], c1, 0, 0, 0);
      c1 = __builtin_amdgcn_mfma_f32_16x16x32_bf16(al[ks], b1h[ks], c1, 0, 0, 0);
    }
    #pragma unroll
    for (int r = 0; r < 4; ++r) {
      int n = m0 + quad * 4 + r;
      hpi[n * 64 + o] = (uint)f2bf(c0[r]) | ((uint)f2bf(c1[r]) << 16);
    }
    #pragma unroll
    for (int r = 0; r < 4; ++r) {
      float pas0 = c0[r] * vas0, pas1 = c1[r] * vas1;
      float pat0 = c0[r] * vat0, pat1 = c1[r] * vat1;
      #pragma unroll
      for (int m = 1; m < 16; m <<= 1) {
        pas0 += __shfl_xor(pas0, m, 64); pas1 += __shfl_xor(pas1, m, 64);
        pat0 += __shfl_xor(pat0, m, 64); pat1 += __shfl_xor(pat1, m, 64);
      }
      if (l15 == 0) {
        part[wv][quad * 4 + r][0] = pas0; part[wv][quad * 4 + r][1] = pas1;
        part[wv][quad * 4 + r][2] = pat0; part[wv][quad * 4 + r][3] = pat1;
      }
    }
    __syncthreads();
    if (tid < 64) {
      int row = tid & 15, which = tid >> 4;
      float v = part[0][row][which] + part[1][row][which]
              + part[2][row][which] + part[3][row][which];
      int n = m0 + row;
      if (which == 0)      attn_src[n * 2]     = v;
      else if (which == 1) attn_src[n * 2 + 1] = v;
      else if (which == 2) attn_trg[n * 2]     = v;
      else                 attn_trg[n * 2 + 1] = v;
    }
    __syncthreads();
  }
}

// 1-block-per-layer scan of the 256 bucket sizes -> bstart[257] + seeded bucket cursors.
__global__ __launch_bounds__(256) void scanb2(const int* __restrict__ bhist,
                                              int* __restrict__ bstart, int* __restrict__ bcur)
{
  const int layer = blockIdx.x;
  const int* bh = bhist + layer * NBUCK;
  int* bs = bstart + layer * (NBUCK + 1);
  int* bc = bcur + layer * NBUCK * 16;
  __shared__ int s[256];
  int v = bh[threadIdx.x];
  s[threadIdx.x] = v;
  __syncthreads();
  for (int d = 1; d < 256; d <<= 1) {
    int t = (threadIdx.x >= d) ? s[threadIdx.x - d] : 0;
    __syncthreads();
    s[threadIdx.x] += t;
    __syncthreads();
  }
  int excl = s[threadIdx.x] - v;
  bs[threadIdx.x] = excl;
  bc[threadIdx.x * 16] = excl;
  if (threadIdx.x == 255) bs[256] = s[255];
}

// Pass B: bin a 2048-edge tile by bucket in LDS, bulk-append contiguous runs per bucket.
// R25: 1024 threads/block (2 edges/thread) — grid is only 1564 blocks, so at 256 threads
// this kernel was capped at ~6.2K waves of barrier-heavy work with a 16-barrier scan on
// the critical path. 16 waves/block shortens each block's serial path ~4x (R22 pattern).
// Scan participation guarded to tid<256; ALL threads hit uniform barriers.
__global__ __launch_bounds__(1024) void bucket2(
    const int* __restrict__ srcA, const int* __restrict__ srcB,
    const int* __restrict__ trgA, const int* __restrict__ trgB,
    int* __restrict__ bcur, uint* __restrict__ pairbufA, uint* __restrict__ pairbufB, int base)
{
  const int layer = (blockIdx.x >= base) ? 1 : 0;
  const int bid = blockIdx.x - layer * base;
  const int* src = layer ? srcB : srcA;
  const int* trg = layer ? trgB : trgA;
  int* bc = bcur + layer * NBUCK * 16;
  uint* pairbuf = layer ? pairbufB : pairbufA;

  __shared__ uint2 plds[TILE];              // (packed entry, bucket id)
  __shared__ int bcnt[NBUCK], bscan[NBUCK], gbase[NBUCK];
  const int tid = threadIdx.x;
  const int b0 = bid * TILE;
  if (tid < NBUCK) bcnt[tid] = 0;
  __syncthreads();
  int myb[2], myr[2];
  uint myp[2];
  #pragma unroll
  for (int j = 0; j < 2; ++j) {
    int e = b0 + j * 1024 + tid;
    myb[j] = -1;
    if (e < N_EDGES) {
      int t = trg[e];
      if (t < N_USER) {
        int b = t / BSZ;
        int tl = t - b * BSZ;               // < 352, fits 9 bits
        myb[j] = b;
        myr[j] = atomicAdd(&bcnt[b], 1);
        myp[j] = (uint)src[e] | ((uint)tl << 17);   // src < 2^17
      }
    }
  }
  __syncthreads();
  if (tid < NBUCK) {
    gbase[tid] = atomicAdd(&bc[tid * 16], bcnt[tid]);
    bscan[tid] = bcnt[tid];
  }
  __syncthreads();
  for (int d = 1; d < 256; d <<= 1) {
    int v = (tid >= d && tid < NBUCK) ? bscan[tid - d] : 0;
    __syncthreads();
    if (tid < NBUCK) bscan[tid] += v;
    __syncthreads();
  }
  #pragma unroll
  for (int j = 0; j < 2; ++j)
    if (myb[j] >= 0) plds[bscan[myb[j]] - bcnt[myb[j]] + myr[j]] = make_uint2(myp[j], (uint)myb[j]);
  __syncthreads();
  int total = bscan[NBUCK - 1];
  for (int i = tid; i < total; i += 1024) {
    uint2 pr = plds[i];
    int b = (int)pr.y;
    int idx = gbase[b] + (i - (bscan[b] - bcnt[b]));
    if (idx >= 0 && idx < N_EDGES) pairbuf[idx] = pr.x;
  }
}

// Pass C: one block per bucket (x2 layers), 1024 threads. Per-target offs in LDS.
// R25: bucket's 352 attn_trg values preloaded into LDS (2.8 KB) — replaces 1.44M random
// 8B global gathers (cross-XCD L2 misses into a 3.2 MB table) with LDS reads.
__global__ __launch_bounds__(1024) void fine2(
    const uint* __restrict__ pairbufA, const uint* __restrict__ pairbufB,
    const int* __restrict__ bstart,
    int* __restrict__ offsA, int* __restrict__ offsB,
    int* __restrict__ csrA,  int* __restrict__ csrB,
    const float* __restrict__ attnsA, const float* __restrict__ attnsB,
    const float* __restrict__ attntA, const float* __restrict__ attntB,
    float2* __restrict__ wgtA, float2* __restrict__ wgtB, int base)
{
  const int layer = (blockIdx.x >= base) ? 1 : 0;
  const int b = blockIdx.x - layer * base;
  const uint* pairbuf = layer ? pairbufB : pairbufA;
  const int* bs = bstart + layer * (NBUCK + 1);
  int* offs = layer ? offsB : offsA;
  int* csr_src = layer ? csrB : csrA;
  const float* attn_src = layer ? attnsB : attnsA;
  const float* attn_trg = layer ? attntB : attntA;
  float2* wgt = layer ? wgtB : wgtA;

  __shared__ int cnt[BSZ + 1];
  __shared__ int cur[BSZ];
  __shared__ float lat[BSZ][2];             // bucket's attn_trg slice
  const int tid = threadIdx.x;
  const int t0 = b * BSZ;
  const int nt = min(BSZ, N_USER - t0);     // 240 for bucket 255
  const int pbeg = bs[b], pend = bs[b + 1];
  const float2* as2 = (const float2*)attn_src;
  const float2* at2 = (const float2*)attn_trg;
  for (int j = tid; j <= BSZ; j += 1024) cnt[j] = 0;
  for (int j = tid; j < BSZ; j += 1024) {   // preload (defensive full-BSZ fill)
    float2 v = at2[min(t0 + j, N_USER - 1)];
    lat[j][0] = v.x; lat[j][1] = v.y;
  }
  __syncthreads();
  for (int i = pbeg + tid; i < pend; i += 1024) {
    int tl = min((int)(pairbuf[i] >> 17), BSZ - 1);
    atomicAdd(&cnt[tl], 1);
  }
  __syncthreads();
  if (tid == 0) {                           // serial exclusive scan, <=352 elems
    int run = 0;
    for (int j = 0; j < nt; ++j) { int c = cnt[j]; cnt[j] = run; run += c; }
    cnt[nt] = run;
  }
  __syncthreads();
  for (int j = tid; j < nt; j += 1024) {
    offs[t0 + j] = pbeg + cnt[j];
    cur[j] = cnt[j];
  }
  if (tid == 0 && t0 + nt == N_USER) offs[N_USER] = pbeg + cnt[nt];
  __syncthreads();
  for (int i = pbeg + tid; i < pend; i += 1024) {
    uint v = pairbuf[i];
    int s = min((int)(v & 0x1FFFFu), N_NODES - 1);
    int tl = min((int)(v >> 17), BSZ - 1);
    float2 as = as2[s];
    float e0 = as.x + lat[tl][0]; e0 = (e0 > 0.f) ? e0 : 0.2f * e0;
    float e1 = as.y + lat[tl][1]; e1 = (e1 > 0.f) ? e1 : 0.2f * e1;
    int p = pbeg + atomicAdd(&cur[tl], 1);
    p = min(max(p, 0), N_EDGES - 1);
    csr_src[p] = s;
    wgt[p] = make_float2(__expf(e0), __expf(e1));
  }
}

// ---------------- per-target accumulation (R9-verbatim: scalarized + XCD affinity) ------
__global__ __launch_bounds__(256) void accum2(
    const int* __restrict__ offsA, const int* __restrict__ offsB,
    const int* __restrict__ csrA,  const int* __restrict__ csrB,
    const float2* __restrict__ wgtA, const float2* __restrict__ wgtB,
    const uint* __restrict__ hpiA, const uint* __restrict__ hpiB,
    float* __restrict__ xA, float* __restrict__ xB, int base, int swz)
{
  int layer, bid;
  if (swz) {
    const int xcd = blockIdx.x & 7, idx = blockIdx.x >> 3;
    layer = xcd >> 2;
    bid = idx * 4 + (xcd & 3);
  } else {
    layer = (blockIdx.x >= base) ? 1 : 0;
    bid = blockIdx.x - layer * base;
  }
  const int* offs = layer ? offsB : offsA;
  const int* csr_src = layer ? csrB : csrA;
  const float2* wgt = layer ? wgtB : wgtA;
  const uint* hpi = layer ? hpiB : hpiA;
  float* x = layer ? xB : xA;

  const int lane = threadIdx.x & 63, wv = threadIdx.x >> 6;
  int n = bid * 4 + wv;
  if (n >= N_USER) return;
  int beg = max(0, offs[n]);
  int end = min(offs[n + 1], N_EDGES);
  beg = __builtin_amdgcn_readfirstlane(beg);   // wave-uniform by construction
  end = __builtin_amdgcn_readfirstlane(end);
  int deg = end - beg;
  float acc0 = 0.f, acc1 = 0.f, den0 = 0.f, den1 = 0.f;
  for (int base2 = 0; base2 < deg; base2 += 64) {
    int rem = min(64, deg - base2);
    int sv = csr_src[beg + base2 + min(lane, rem - 1)];  // coalesced; lanes>=rem dup last
    sv = min(max(sv, 0), N_NODES - 1);                   // clamp once, pre-broadcast
    int nfull = rem & ~7;
    for (int j = 0; j < nfull; j += 8) {                 // lean full blocks
      int ss[8]; uint pv[8]; float2 W[8];
      #pragma unroll
      for (int u = 0; u < 8; ++u) ss[u] = __builtin_amdgcn_readlane(sv, j + u);  // SGPR
      #pragma unroll
      for (int u = 0; u < 8; ++u) pv[u] = (hpi + (size_t)ss[u] * 64)[lane];      // saddr
      #pragma unroll
      for (int u = 0; u < 8; ++u) W[u] = wgt[beg + base2 + j + u];               // s_load
      #pragma unroll
      for (int u = 0; u < 8; ++u) {
        den0 += W[u].x; den1 += W[u].y;
        acc0 += W[u].x * bf2f((ushort)(pv[u] & 0xffffu));
        acc1 += W[u].y * bf2f((ushort)(pv[u] >> 16));
      }
    }
    if (nfull < rem) {                                   // single masked tail block
      int j = nfull;
      int ss[8]; uint pv[8]; float2 W[8];
      #pragma unroll
      for (int u = 0; u < 8; ++u) ss[u] = __builtin_amdgcn_readlane(sv, min(j + u, rem - 1));
      #pragma unroll
      for (int u = 0; u < 8; ++u) pv[u] = (hpi + (size_t)ss[u] * 64)[lane];
      #pragma unroll
      for (int u = 0; u < 8; ++u)
        W[u] = (j + u < rem) ? wgt[beg + base2 + j + u] : make_float2(0.f, 0.f);
      #pragma unroll
      for (int u = 0; u < 8; ++u) {
        den0 += W[u].x; den1 += W[u].y;
        acc0 += W[u].x * bf2f((ushort)(pv[u] & 0xffffu));
        acc1 += W[u].y * bf2f((ushort)(pv[u] >> 16));
      }
    }
  }
  x[n * 64 + lane] = 0.5f * (acc0 / (den0 + 1e-16f) + acc1 / (den1 + 1e-16f));
}

// ---------------- final: 3 MFMA GEMMs + fused epilogue (R10-verbatim, barrier diet) -----
__global__ __launch_bounds__(256) void final_mfma(
    const float* __restrict__ h, const float* __restrict__ x0, const float* __restrict__ x1,
    const float* __restrict__ aa_w1, const float* __restrict__ aa_w2, const float* __restrict__ aa_m,
    const float* __restrict__ fc_w, const float* __restrict__ fc_b, float* __restrict__ out)
{
  __shared__ float aam_s[64], fcw_s[384], fcb_s[2];
  __shared__ float scw0[2][4][16], scw1[2][4][16];
  const int tid = threadIdx.x;
  if (tid < 64)  aam_s[tid] = aa_m[tid];
  for (int i = tid; i < 384; i += 256) fcw_s[i] = fc_w[i];
  if (tid < 2)   fcb_s[tid] = fc_b[tid];
  const int lane = tid & 63, wv = tid >> 6, quad = lane >> 4, l15 = lane & 15;
  const int d = wv * 16 + l15;
  short8 b1h[2], b1l[2], b2h[2], b2l[2];
  #pragma unroll
  for (int ks = 0; ks < 2; ++ks) {
    load_split8(aa_w1 + d * 64 + quad * 8 + ks * 32, b1h[ks], b1l[ks]);
    load_split8(aa_w2 + d * 64 + quad * 8 + ks * 32, b2h[ks], b2l[ks]);
  }
  __syncthreads();
  int pp = 0;
  for (int t = blockIdx.x; t < N_USER / 16; t += gridDim.x) {
    int m0 = t * 16, arow = m0 + l15;
    const int erow = m0 + wv * 4 + quad;
    float4 ev0 = *(const float4*)(x0 + erow * 64 + l15 * 4);
    float4 ev1 = *(const float4*)(x1 + erow * 64 + l15 * 4);
    short8 ahh[2], ahl[2], a0h[2], a0l[2], a1h[2], a1l[2];
    #pragma unroll
    for (int ks = 0; ks < 2; ++ks) {
      load_split8(h  + arow * 64 + quad * 8 + ks * 32, ahh[ks], ahl[ks]);
      load_split8(x0 + arow * 64 + quad * 8 + ks * 32, a0h[ks], a0l[ks]);
      load_split8(x1 + arow * 64 + quad * 8 + ks * 32, a1h[ks], a1l[ks]);
    }
    floatx4 t1a = {0.f,0.f,0.f,0.f}, t20a = {0.f,0.f,0.f,0.f}, t21a = {0.f,0.f,0.f,0.f};
    #pragma unroll
    for (int ks = 0; ks < 2; ++ks) {
      t1a  = __builtin_amdgcn_mfma_f32_16x16x32_bf16(ahh[ks], b1h[ks], t1a, 0, 0, 0);
      t1a  = __builtin_amdgcn_mfma_f32_16x16x32_bf16(ahh[ks], b1l[ks], t1a, 0, 0, 0);
      t1a  = __builtin_amdgcn_mfma_f32_16x16x32_bf16(ahl[ks], b1h[ks], t1a, 0, 0, 0);
      t20a = __builtin_amdgcn_mfma_f32_16x16x32_bf16(a0h[ks], b2h[ks], t20a, 0, 0, 0);
      t20a = __builtin_amdgcn_mfma_f32_16x16x32_bf16(a0h[ks], b2l[ks], t20a, 0, 0, 0);
      t20a = __builtin_amdgcn_mfma_f32_16x16x32_bf16(a0l[ks], b2h[ks], t20a, 0, 0, 0);
      t21a = __builtin_amdgcn_mfma_f32_16x16x32_bf16(a1h[ks], b2h[ks], t21a, 0, 0, 0);
      t21a = __builtin_amdgcn_mfma_f32_16x16x32_bf16(a1h[ks], b2l[ks], t21a, 0, 0, 0);
      t21a = __builtin_amdgcn_mfma_f32_16x16x32_bf16(a1l[ks], b2h[ks], t21a, 0, 0, 0);
    }
    float am = aam_s[d];
    #pragma unroll
    for (int r = 0; r < 4; ++r) {
      float q0 = fast_tanh(t1a[r] + t20a[r]);
      float q1 = fast_tanh(t1a[r] + t21a[r]);
      float p0 = q0 * am, p1 = q1 * am;
      #pragma unroll
      for (int m = 1; m < 16; m <<= 1) { p0 += __shfl_xor(p0, m, 64); p1 += __shfl_xor(p1, m, 64); }
      if (l15 == 0) { scw0[pp][wv][quad * 4 + r] = p0; scw1[pp][wv][quad * 4 + r] = p1; }
    }
    __syncthreads();
    {
      int row = wv * 4 + quad, n = m0 + row;
      float s0 = scw0[pp][0][row] + scw0[pp][1][row] + scw0[pp][2][row] + scw0[pp][3][row];
      float s1 = scw1[pp][0][row] + scw1[pp][1][row] + scw1[pp][2][row] + scw1[pp][3][row];
      float mx = fmaxf(s0, s1);
      float e0 = __expf(s0 - mx), e1 = __expf(s1 - mx);
      float inv = 1.f / (e0 + e1);
      float b0 = e0 * inv, b1 = e1 * inv;
      float a0[4] = {ev0.x, ev0.y, ev0.z, ev0.w};
      float a1[4] = {ev1.x, ev1.y, ev1.z, ev1.w};
      float pc0 = 0.f, pc1 = 0.f;
      #pragma unroll
      for (int c = 0; c < 4; ++c) {
        int o = l15 * 4 + c;
        float fv = b0 * a0[c] + b1 * a1[c];
        pc0 += fcw_s[o] * a0[c] + fcw_s[64 + o] * a1[c] + fcw_s[128 + o] * fv;
        pc1 += fcw_s[192 + o] * a0[c] + fcw_s[256 + o] * a1[c] + fcw_s[320 + o] * fv;
      }
      #pragma unroll
      for (int m = 1; m < 16; m <<= 1) { pc0 += __shfl_xor(pc0, m, 64); pc1 += __shfl_xor(pc1, m, 64); }
      if (l15 == 0) {
        float l0 = pc0 + fcb_s[0], l1 = pc1 + fcb_s[1];
        float lm = fmaxf(l0, l1);
        float lse = lm + logf(__expf(l0 - lm) + __expf(l1 - lm));
        out[n * 2] = l0 - lse;
        out[n * 2 + 1] = l1 - lse;
      }
    }
    pp ^= 1;                                // no trailing barrier: next tile writes other buffer
  }
}

extern "C" void kernel_launch(void* const* d_in, const int* in_sizes, int n_in,
                              void* d_out, int out_size, void* d_ws, size_t ws_size,
                              hipStream_t stream)
{
  const float* h     = (const float*)d_in[0];
  const int*   src0  = (const int*)d_in[1];
  const int*   trg0  = (const int*)d_in[2];
  const int*   src1  = (const int*)d_in[3];
  const int*   trg1  = (const int*)d_in[4];
  const float* w0    = (const float*)d_in[5];
  const float* asrc0 = (const float*)d_in[6];
  const float* atrg0 = (const float*)d_in[7];
  const float* w1    = (const float*)d_in[8];
  const float* asrc1 = (const float*)d_in[9];
  const float* atrg1 = (const float*)d_in[10];
  const float* aa_w1 = (const float*)d_in[11];
  const float* aa_w2 = (const float*)d_in[12];
  const float* aa_m  = (const float*)d_in[13];
  const float* fc_w  = (const float*)d_in[14];
  const float* fc_b  = (const float*)d_in[15];
  float* out = (float*)d_out;

  // both-layers-resident needs ~155 MB (packed pairbuf); fall back if ws is tight
  const int nl = (ws_size >= (size_t)162 * 1024 * 1024) ? 2 : 1;
  const size_t L = (size_t)(nl - 1);   // 1 in concurrent mode, 0 in fallback

  char* ws = (char*)d_ws;
  size_t off = 0;
  auto alloc = [&](size_t bytes) -> void* {
    void* p = ws + off;
    off = (off + bytes + 255) & ~(size_t)255;
    return p;
  };
  uint*   hpi      = (uint*)alloc((size_t)nl * N_NODES * 64 * 4);
  float*  attn_src = (float*)alloc((size_t)nl * N_NODES * 2 * 4);
  float*  attn_trg = (float*)alloc((size_t)nl * N_NODES * 2 * 4);
  float*  x0       = (float*)alloc((size_t)N_USER * 64 * 4);
  float*  x1       = (float*)alloc((size_t)N_USER * 64 * 4);
  int*    offs     = (int*)alloc((size_t)nl * (N_USER + 1) * 4);
  int*    csr      = (int*)alloc((size_t)nl * N_EDGES * 4);
  uint*   pairbuf  = (uint*)alloc((size_t)nl * N_EDGES * 4);    // packed 4B entries
  float2* wgt      = (float2*)alloc((size_t)nl * N_EDGES * 8);
  int*    bhist    = (int*)alloc((size_t)2 * NBUCK * 4);
  int*    bstart   = (int*)alloc((size_t)2 * (NBUCK + 1) * 4);
  int*    bcur     = (int*)alloc((size_t)2 * NBUCK * 16 * 4);

  uint*   hpi1     = hpi + L * (size_t)N_NODES * 64;
  float*  attns1   = attn_src + L * (size_t)N_NODES * 2;
  float*  attnt1   = attn_trg + L * (size_t)N_NODES * 2;
  int*    offs1    = offs + L * (size_t)(N_USER + 1);
  int*    csr1     = csr + L * (size_t)N_EDGES;
  uint*   pairbuf1 = pairbuf + L * (size_t)N_EDGES;
  float2* wgt1     = wgt + L * (size_t)N_EDGES;

  if (nl == 2) {
    hipMemsetAsync(bhist, 0, (size_t)2 * NBUCK * 4, stream);
    hipLaunchKernelGGL(stage1, dim3(2 * HPB + 2 * TBLK), dim3(256), 0, stream,
                       h, w0, w1, asrc0, asrc1, atrg0, atrg1,
                       hpi, hpi1, attn_src, attns1, attn_trg, attnt1,
                       trg0, trg1, bhist, 2 * HPB, HPB, TBLK);
    hipLaunchKernelGGL(scanb2, dim3(2), dim3(256), 0, stream, bhist, bstart, bcur);
    hipLaunchKernelGGL(bucket2, dim3(2 * TBLK), dim3(1024), 0, stream,
                       src0, src1, trg0, trg1, bcur, pairbuf, pairbuf1, TBLK);
    hipLaunchKernelGGL(fine2, dim3(2 * NBUCK), dim3(1024), 0, stream,
                       pairbuf, pairbuf1, bstart, offs, offs1, csr, csr1,
                       attn_src, attns1, attn_trg, attnt1, wgt, wgt1, NBUCK);
    hipLaunchKernelGGL(accum2, dim3(2 * ACCB), dim3(256), 0, stream,
                       offs, offs1, csr, csr1, wgt, wgt1, hpi, hpi1, x0, x1, ACCB, 1);
  } else {
    for (int layer = 0; layer < 2; ++layer) {
      const float* w    = layer ? w1 : w0;
      const float* asrc = layer ? asrc1 : asrc0;
      const float* atrg = layer ? atrg1 : atrg0;
      const int*   src  = layer ? src1 : src0;
      const int*   trg  = layer ? trg1 : trg0;
      float*       x    = layer ? x1 : x0;
      hipMemsetAsync(bhist, 0, (size_t)NBUCK * 4, stream);
      hipLaunchKernelGGL(stage1, dim3(HPB + TBLK), dim3(256), 0, stream,
                         h, w, w, asrc, asrc, atrg, atrg,
                         hpi, hpi, attn_src, attn_src, attn_trg, attn_trg,
                         trg, trg, bhist, HPB, HPB, TBLK);
      hipLaunchKernelGGL(scanb2, dim3(1), dim3(256), 0, stream, bhist, bstart, bcur);
      hipLaunchKernelGGL(bucket2, dim3(TBLK), dim3(1024), 0, stream,
                         src, src, trg, trg, bcur, pairbuf, pairbuf, TBLK);
      hipLaunchKernelGGL(fine2, dim3(NBUCK), dim3(1024), 0, stream,
                         pairbuf, pairbuf, bstart, offs, offs, csr, csr,
                         attn_src, attn_src, attn_trg, attn_trg, wgt, wgt, NBUCK);
      hipLaunchKernelGGL(accum2, dim3(ACCB), dim3(256), 0, stream,
                         offs, offs, csr, csr, wgt, wgt, hpi, hpi, x, x, ACCB, 0);
    }
  }
  hipLaunchKernelGGL(final_mfma, dim3(1875), dim3(256), 0, stream,
                     h, x0, x1, aa_w1, aa_w2, aa_m, fc_w, fc_b, out);
}

// Round 16
// 400.541 us; speedup vs baseline: 1.0749x; 1.0556x over previous
//
#include <hip/hip_runtime.h>
#include <hip/hip_bf16.h>
#include <math.h>

#define N_NODES 100000
#define N_EDGES 1600000
#define N_USER  90000
#define NBUCK   256
#define BSZ     352   // targets per bucket; 256*352 = 90112 >= N_USER
#define TILE    2048  // edges per bucket/bhist block
#define TBLK    782   // (N_EDGES + TILE - 1) / TILE
#define ACCB    22500 // N_USER / 4
#define HPB     1024  // hp base grid (per layer)

typedef __attribute__((ext_vector_type(8))) short  short8;   // 8 bf16 (4 VGPRs) MFMA A/B frag
typedef __attribute__((ext_vector_type(4))) float  floatx4;  // MFMA C/D frag
typedef unsigned int  uint;
typedef unsigned short ushort;

__device__ __forceinline__ ushort f2bf(float x) {            // RNE fp32 -> bf16
  uint u = __float_as_uint(x);
  u += 0x7fffu + ((u >> 16) & 1u);
  return (ushort)(u >> 16);
}
__device__ __forceinline__ float bf2f(ushort v) { return __uint_as_float(((uint)v) << 16); }

__device__ __forceinline__ void split8(const float v[8], short8& hi, short8& lo) {
  #pragma unroll
  for (int j = 0; j < 8; ++j) {
    ushort h = f2bf(v[j]);
    hi[j] = (short)h;
    lo[j] = (short)f2bf(v[j] - bf2f(h));
  }
}
__device__ __forceinline__ void load_split8(const float* p, short8& hi, short8& lo) {
  const float4* q = (const float4*)p;
  float4 a = q[0], b = q[1];
  float v[8] = {a.x, a.y, a.z, a.w, b.x, b.y, b.z, b.w};
  split8(v, hi, lo);
}
__device__ __forceinline__ float fast_tanh(float x) {
  float t = __expf(2.f * x);
  return 1.f - 2.f / (t + 1.f);
}

// ---------------- stage1: hp (MFMA) for both layers  ||  bhist for both layers ----------
__global__ __launch_bounds__(256) void stage1(
    const float* __restrict__ h,
    const float* __restrict__ wA,  const float* __restrict__ wB,
    const float* __restrict__ asA, const float* __restrict__ asB,
    const float* __restrict__ atA, const float* __restrict__ atB,
    uint* __restrict__ hpiA, uint* __restrict__ hpiB,
    float* __restrict__ attnsA, float* __restrict__ attnsB,
    float* __restrict__ attntA, float* __restrict__ attntB,
    const int* __restrict__ trgA, const int* __restrict__ trgB,
    int* __restrict__ bhist,
    int hpTot, int hpBase, int bhBase)
{
  __shared__ float part[4][16][4];          // hp: [wave][row][as0,as1,at0,at1]
  __shared__ int hh[NBUCK];                 // bhist
  const int tid = threadIdx.x;

  if (blockIdx.x >= hpTot) {                // ---- bhist branch ----
    const int b2 = blockIdx.x - hpTot;
    const int layer = (b2 >= bhBase) ? 1 : 0;
    const int bid = b2 - layer * bhBase;
    const int* trg = layer ? trgB : trgA;
    int* bh = bhist + layer * NBUCK;
    hh[tid] = 0;
    __syncthreads();
    const int b0 = bid * TILE;
    #pragma unroll
    for (int j = 0; j < 8; ++j) {
      int e = b0 + j * 256 + tid;
      if (e < N_EDGES) {
        int t = trg[e];
        if (t < N_USER) atomicAdd(&hh[t / BSZ], 1);
      }
    }
    __syncthreads();
    if (hh[tid]) atomicAdd(&bh[tid], hh[tid]);
    return;
  }

  // ---- hp branch ----
  const int layer = (blockIdx.x >= hpBase) ? 1 : 0;
  const int bid = blockIdx.x - layer * hpBase;
  const float* w     = layer ? wB : wA;
  const float* a_src = layer ? asB : asA;
  const float* a_trg = layer ? atB : atA;
  uint*  hpi      = layer ? hpiB : hpiA;
  float* attn_src = layer ? attnsB : attnsA;
  float* attn_trg = layer ? attntB : attntA;

  const int lane = tid & 63, wv = tid >> 6;
  const int quad = lane >> 4, l15 = lane & 15;
  const int o = wv * 16 + l15;              // wave's 16-col slice of the 64 outputs
  const float vas0 = a_src[o], vas1 = a_src[64 + o];
  const float vat0 = a_trg[o], vat1 = a_trg[64 + o];
  short8 b0h[2], b0l[2], b1h[2], b1l[2];    // B frags: head0/head1 x ksteps
  #pragma unroll
  for (int ks = 0; ks < 2; ++ks) {
    float v0[8], v1[8];
    #pragma unroll
    for (int j = 0; j < 8; ++j) {
      int k = quad * 8 + j + ks * 32;       // f index
      v0[j] = w[k * 64 + o];                // w[0][f][o]
      v1[j] = w[4096 + k * 64 + o];         // w[1][f][o]
    }
    split8(v0, b0h[ks], b0l[ks]);
    split8(v1, b1h[ks], b1l[ks]);
  }
  for (int t = bid; t < N_NODES / 16; t += hpBase) {
    int m0 = t * 16, arow = m0 + l15;
    short8 ah[2], al[2];
    #pragma unroll
    for (int ks = 0; ks < 2; ++ks)
      load_split8(h + arow * 64 + quad * 8 + ks * 32, ah[ks], al[ks]);
    floatx4 c0 = {0.f, 0.f, 0.f, 0.f}, c1 = {0.f, 0.f, 0.f, 0.f};
    #pragma unroll
    for (int ks = 0; ks < 2; ++ks) {
      c0 = __builtin_amdgcn_mfma_f32_16x16x32_bf16(ah[ks], b0h[ks], c0, 0, 0, 0);
      c0 = __builtin_amdgcn_mfma_f32_16x16x32_bf16(ah[ks], b0l[ks], c0, 0, 0, 0);
      c0 = __builtin_amdgcn_mfma_f32_16x16x32_bf16(al[ks], b0h[ks], c0, 0, 0, 0);
      c1 = __builtin_amdgcn_mfma_f32_16x16x32_bf16(ah[ks], b1h[ks], c1, 0, 0, 0);
      c1 = __builtin_amdgcn_mfma_f32_16x16x32_bf16(ah[ks], b1l[ks], c1, 0, 0, 0);
      c1 = __builtin_amdgcn_mfma_f32_16x16x32_bf16(al[ks], b1h[ks], c1, 0, 0, 0);
    }
    #pragma unroll
    for (int r = 0; r < 4; ++r) {
      int n = m0 + quad * 4 + r;
      hpi[n * 64 + o] = (uint)f2bf(c0[r]) | ((uint)f2bf(c1[r]) << 16);
    }
    #pragma unroll
    for (int r = 0; r < 4; ++r) {
      float pas0 = c0[r] * vas0, pas1 = c1[r] * vas1;
      float pat0 = c0[r] * vat0, pat1 = c1[r] * vat1;
      #pragma unroll
      for (int m = 1; m < 16; m <<= 1) {
        pas0 += __shfl_xor(pas0, m, 64); pas1 += __shfl_xor(pas1, m, 64);
        pat0 += __shfl_xor(pat0, m, 64); pat1 += __shfl_xor(pat1, m, 64);
      }
      if (l15 == 0) {
        part[wv][quad * 4 + r][0] = pas0; part[wv][quad * 4 + r][1] = pas1;
        part[wv][quad * 4 + r][2] = pat0; part[wv][quad * 4 + r][3] = pat1;
      }
    }
    __syncthreads();
    if (tid < 64) {
      int row = tid & 15, which = tid >> 4;
      float v = part[0][row][which] + part[1][row][which]
              + part[2][row][which] + part[3][row][which];
      int n = m0 + row;
      if (which == 0)      attn_src[n * 2]     = v;
      else if (which == 1) attn_src[n * 2 + 1] = v;
      else if (which == 2) attn_trg[n * 2]     = v;
      else                 attn_trg[n * 2 + 1] = v;
    }
    __syncthreads();
  }
}

// 1-block-per-layer scan of the 256 bucket sizes -> bstart[257] + seeded bucket cursors.
__global__ __launch_bounds__(256) void scanb2(const int* __restrict__ bhist,
                                              int* __restrict__ bstart, int* __restrict__ bcur)
{
  const int layer = blockIdx.x;
  const int* bh = bhist + layer * NBUCK;
  int* bs = bstart + layer * (NBUCK + 1);
  int* bc = bcur + layer * NBUCK * 16;
  __shared__ int s[256];
  int v = bh[threadIdx.x];
  s[threadIdx.x] = v;
  __syncthreads();
  for (int d = 1; d < 256; d <<= 1) {
    int t = (threadIdx.x >= d) ? s[threadIdx.x - d] : 0;
    __syncthreads();
    s[threadIdx.x] += t;
    __syncthreads();
  }
  int excl = s[threadIdx.x] - v;
  bs[threadIdx.x] = excl;
  bc[threadIdx.x * 16] = excl;
  if (threadIdx.x == 255) bs[256] = s[255];
}

// Pass B: bin a 2048-edge tile by bucket in LDS (R15-proven 1024-thread version).
__global__ __launch_bounds__(1024) void bucket2(
    const int* __restrict__ srcA, const int* __restrict__ srcB,
    const int* __restrict__ trgA, const int* __restrict__ trgB,
    int* __restrict__ bcur, uint* __restrict__ pairbufA, uint* __restrict__ pairbufB, int base)
{
  const int layer = (blockIdx.x >= base) ? 1 : 0;
  const int bid = blockIdx.x - layer * base;
  const int* src = layer ? srcB : srcA;
  const int* trg = layer ? trgB : trgA;
  int* bc = bcur + layer * NBUCK * 16;
  uint* pairbuf = layer ? pairbufB : pairbufA;

  __shared__ uint2 plds[TILE];              // (packed entry, bucket id)
  __shared__ int bcnt[NBUCK], bscan[NBUCK], gbase[NBUCK];
  const int tid = threadIdx.x;
  const int b0 = bid * TILE;
  if (tid < NBUCK) bcnt[tid] = 0;
  __syncthreads();
  int myb[2], myr[2];
  uint myp[2];
  #pragma unroll
  for (int j = 0; j < 2; ++j) {
    int e = b0 + j * 1024 + tid;
    myb[j] = -1;
    if (e < N_EDGES) {
      int t = trg[e];
      if (t < N_USER) {
        int b = t / BSZ;
        int tl = t - b * BSZ;               // < 352, fits 9 bits
        myb[j] = b;
        myr[j] = atomicAdd(&bcnt[b], 1);
        myp[j] = (uint)src[e] | ((uint)tl << 17);   // src < 2^17
      }
    }
  }
  __syncthreads();
  if (tid < NBUCK) {
    gbase[tid] = atomicAdd(&bc[tid * 16], bcnt[tid]);
    bscan[tid] = bcnt[tid];
  }
  __syncthreads();
  for (int d = 1; d < 256; d <<= 1) {
    int v = (tid >= d && tid < NBUCK) ? bscan[tid - d] : 0;
    __syncthreads();
    if (tid < NBUCK) bscan[tid] += v;
    __syncthreads();
  }
  #pragma unroll
  for (int j = 0; j < 2; ++j)
    if (myb[j] >= 0) plds[bscan[myb[j]] - bcnt[myb[j]] + myr[j]] = make_uint2(myp[j], (uint)myb[j]);
  __syncthreads();
  int total = bscan[NBUCK - 1];
  for (int i = tid; i < total; i += 1024) {
    uint2 pr = plds[i];
    int b = (int)pr.y;
    int idx = gbase[b] + (i - (bscan[b] - bcnt[b]));
    if (idx >= 0 && idx < N_EDGES) pairbuf[idx] = pr.x;
  }
}

// Pass C (R26): pure count/scan/scatter — the attn gathers, exp, and wgt writes moved
// into accum2 (weights recomputed there at coalesced cost). 1024 threads.
__global__ __launch_bounds__(1024) void fine2(
    const uint* __restrict__ pairbufA, const uint* __restrict__ pairbufB,
    const int* __restrict__ bstart,
    int* __restrict__ offsA, int* __restrict__ offsB,
    int* __restrict__ csrA,  int* __restrict__ csrB, int base)
{
  const int layer = (blockIdx.x >= base) ? 1 : 0;
  const int b = blockIdx.x - layer * base;
  const uint* pairbuf = layer ? pairbufB : pairbufA;
  const int* bs = bstart + layer * (NBUCK + 1);
  int* offs = layer ? offsB : offsA;
  int* csr_src = layer ? csrB : csrA;

  __shared__ int cnt[BSZ + 1];
  __shared__ int cur[BSZ];
  const int tid = threadIdx.x;
  const int t0 = b * BSZ;
  const int nt = min(BSZ, N_USER - t0);     // 240 for bucket 255
  const int pbeg = bs[b], pend = bs[b + 1];
  for (int j = tid; j <= BSZ; j += 1024) cnt[j] = 0;
  __syncthreads();
  for (int i = pbeg + tid; i < pend; i += 1024) {
    int tl = min((int)(pairbuf[i] >> 17), BSZ - 1);
    atomicAdd(&cnt[tl], 1);
  }
  __syncthreads();
  if (tid == 0) {                           // serial exclusive scan, <=352 elems
    int run = 0;
    for (int j = 0; j < nt; ++j) { int c = cnt[j]; cnt[j] = run; run += c; }
    cnt[nt] = run;
  }
  __syncthreads();
  for (int j = tid; j < nt; j += 1024) {
    offs[t0 + j] = pbeg + cnt[j];
    cur[j] = cnt[j];
  }
  if (tid == 0 && t0 + nt == N_USER) offs[N_USER] = pbeg + cnt[nt];
  __syncthreads();
  for (int i = pbeg + tid; i < pend; i += 1024) {
    uint v = pairbuf[i];
    int s = min((int)(v & 0x1FFFFu), N_NODES - 1);
    int tl = min((int)(v >> 17), BSZ - 1);
    int p = pbeg + atomicAdd(&cur[tl], 1);
    p = min(max(p, 0), N_EDGES - 1);
    csr_src[p] = s;
  }
}

// ---------------- per-target accumulation (R26: weights computed in-kernel) ------------
// Chunk prologue: lane j holds edge j's src -> one as2 gather (800KB L2-resident table),
// wave-uniform at2[n], 2 expf per edge (1 lane each), ghost lanes zeroed once. FMA loop
// broadcasts weights via v_readlane (R7-proven SALU path, not R6's ds_bpermute). den =
// butterfly per chunk (positive values, reassociation only). Full/tail blocks identical.
__global__ __launch_bounds__(256) void accum2(
    const int* __restrict__ offsA, const int* __restrict__ offsB,
    const int* __restrict__ csrA,  const int* __restrict__ csrB,
    const float* __restrict__ attnsA, const float* __restrict__ attnsB,
    const float* __restrict__ attntA, const float* __restrict__ attntB,
    const uint* __restrict__ hpiA, const uint* __restrict__ hpiB,
    float* __restrict__ xA, float* __restrict__ xB, int base, int swz)
{
  int layer, bid;
  if (swz) {
    const int xcd = blockIdx.x & 7, idx = blockIdx.x >> 3;
    layer = xcd >> 2;
    bid = idx * 4 + (xcd & 3);
  } else {
    layer = (blockIdx.x >= base) ? 1 : 0;
    bid = blockIdx.x - layer * base;
  }
  const int* offs = layer ? offsB : offsA;
  const int* csr_src = layer ? csrB : csrA;
  const float2* as2 = (const float2*)(layer ? attnsB : attnsA);
  const float2* at2 = (const float2*)(layer ? attntB : attntA);
  const uint* hpi = layer ? hpiB : hpiA;
  float* x = layer ? xB : xA;

  const int lane = threadIdx.x & 63, wv = threadIdx.x >> 6;
  int n = bid * 4 + wv;
  if (n >= N_USER) return;
  int beg = max(0, offs[n]);
  int end = min(offs[n + 1], N_EDGES);
  beg = __builtin_amdgcn_readfirstlane(beg);   // wave-uniform by construction
  end = __builtin_amdgcn_readfirstlane(end);
  int deg = end - beg;
  const float2 at = at2[n];                    // wave-uniform target logit
  float acc0 = 0.f, acc1 = 0.f, den0 = 0.f, den1 = 0.f;
  for (int base2 = 0; base2 < deg; base2 += 64) {
    int rem = min(64, deg - base2);
    int sv = csr_src[beg + base2 + min(lane, rem - 1)];  // coalesced; lanes>=rem dup last
    sv = min(max(sv, 0), N_NODES - 1);                   // clamp once, pre-broadcast
    // per-lane weight for edge base2+lane (ghost lanes carry 0)
    float2 as = as2[sv];
    float e0 = as.x + at.x; e0 = (e0 > 0.f) ? e0 : 0.2f * e0;
    float e1 = as.y + at.y; e1 = (e1 > 0.f) ? e1 : 0.2f * e1;
    float wx = (lane < rem) ? __expf(e0) : 0.f;
    float wy = (lane < rem) ? __expf(e1) : 0.f;
    {                                                    // den: butterfly (ghosts = 0)
      float dx = wx, dy = wy;
      #pragma unroll
      for (int m = 1; m < 64; m <<= 1) { dx += __shfl_xor(dx, m, 64); dy += __shfl_xor(dy, m, 64); }
      den0 += dx; den1 += dy;
    }
    const int wxi = __float_as_int(wx), wyi = __float_as_int(wy);
    for (int j = 0; j < rem; j += 8) {                   // uniform lean 8-wide blocks
      int ss[8]; uint pv[8]; float Wx[8], Wy[8];
      #pragma unroll
      for (int u = 0; u < 8; ++u) ss[u] = __builtin_amdgcn_readlane(sv, j + u);  // SGPR
      #pragma unroll
      for (int u = 0; u < 8; ++u) pv[u] = (hpi + (size_t)ss[u] * 64)[lane];      // saddr
      #pragma unroll
      for (int u = 0; u < 8; ++u) {
        Wx[u] = __int_as_float(__builtin_amdgcn_readlane(wxi, j + u));
        Wy[u] = __int_as_float(__builtin_amdgcn_readlane(wyi, j + u));
      }
      #pragma unroll
      for (int u = 0; u < 8; ++u) {
        acc0 += Wx[u] * bf2f((ushort)(pv[u] & 0xffffu));
        acc1 += Wy[u] * bf2f((ushort)(pv[u] >> 16));
      }
    }
  }
  x[n * 64 + lane] = 0.5f * (acc0 / (den0 + 1e-16f) + acc1 / (den1 + 1e-16f));
}

// ---------------- final: 3 MFMA GEMMs + fused epilogue (R10-verbatim, barrier diet) -----
__global__ __launch_bounds__(256) void final_mfma(
    const float* __restrict__ h, const float* __restrict__ x0, const float* __restrict__ x1,
    const float* __restrict__ aa_w1, const float* __restrict__ aa_w2, const float* __restrict__ aa_m,
    const float* __restrict__ fc_w, const float* __restrict__ fc_b, float* __restrict__ out)
{
  __shared__ float aam_s[64], fcw_s[384], fcb_s[2];
  __shared__ float scw0[2][4][16], scw1[2][4][16];
  const int tid = threadIdx.x;
  if (tid < 64)  aam_s[tid] = aa_m[tid];
  for (int i = tid; i < 384; i += 256) fcw_s[i] = fc_w[i];
  if (tid < 2)   fcb_s[tid] = fc_b[tid];
  const int lane = tid & 63, wv = tid >> 6, quad = lane >> 4, l15 = lane & 15;
  const int d = wv * 16 + l15;
  short8 b1h[2], b1l[2], b2h[2], b2l[2];
  #pragma unroll
  for (int ks = 0; ks < 2; ++ks) {
    load_split8(aa_w1 + d * 64 + quad * 8 + ks * 32, b1h[ks], b1l[ks]);
    load_split8(aa_w2 + d * 64 + quad * 8 + ks * 32, b2h[ks], b2l[ks]);
  }
  __syncthreads();
  int pp = 0;
  for (int t = blockIdx.x; t < N_USER / 16; t += gridDim.x) {
    int m0 = t * 16, arow = m0 + l15;
    const int erow = m0 + wv * 4 + quad;
    float4 ev0 = *(const float4*)(x0 + erow * 64 + l15 * 4);
    float4 ev1 = *(const float4*)(x1 + erow * 64 + l15 * 4);
    short8 ahh[2], ahl[2], a0h[2], a0l[2], a1h[2], a1l[2];
    #pragma unroll
    for (int ks = 0; ks < 2; ++ks) {
      load_split8(h  + arow * 64 + quad * 8 + ks * 32, ahh[ks], ahl[ks]);
      load_split8(x0 + arow * 64 + quad * 8 + ks * 32, a0h[ks], a0l[ks]);
      load_split8(x1 + arow * 64 + quad * 8 + ks * 32, a1h[ks], a1l[ks]);
    }
    floatx4 t1a = {0.f,0.f,0.f,0.f}, t20a = {0.f,0.f,0.f,0.f}, t21a = {0.f,0.f,0.f,0.f};
    #pragma unroll
    for (int ks = 0; ks < 2; ++ks) {
      t1a  = __builtin_amdgcn_mfma_f32_16x16x32_bf16(ahh[ks], b1h[ks], t1a, 0, 0, 0);
      t1a  = __builtin_amdgcn_mfma_f32_16x16x32_bf16(ahh[ks], b1l[ks], t1a, 0, 0, 0);
      t1a  = __builtin_amdgcn_mfma_f32_16x16x32_bf16(ahl[ks], b1h[ks], t1a, 0, 0, 0);
      t20a = __builtin_amdgcn_mfma_f32_16x16x32_bf16(a0h[ks], b2h[ks], t20a, 0, 0, 0);
      t20a = __builtin_amdgcn_mfma_f32_16x16x32_bf16(a0h[ks], b2l[ks], t20a, 0, 0, 0);
      t20a = __builtin_amdgcn_mfma_f32_16x16x32_bf16(a0l[ks], b2h[ks], t20a, 0, 0, 0);
      t21a = __builtin_amdgcn_mfma_f32_16x16x32_bf16(a1h[ks], b2h[ks], t21a, 0, 0, 0);
      t21a = __builtin_amdgcn_mfma_f32_16x16x32_bf16(a1h[ks], b2l[ks], t21a, 0, 0, 0);
      t21a = __builtin_amdgcn_mfma_f32_16x16x32_bf16(a1l[ks], b2h[ks], t21a, 0, 0, 0);
    }
    float am = aam_s[d];
    #pragma unroll
    for (int r = 0; r < 4; ++r) {
      float q0 = fast_tanh(t1a[r] + t20a[r]);
      float q1 = fast_tanh(t1a[r] + t21a[r]);
      float p0 = q0 * am, p1 = q1 * am;
      #pragma unroll
      for (int m = 1; m < 16; m <<= 1) { p0 += __shfl_xor(p0, m, 64); p1 += __shfl_xor(p1, m, 64); }
      if (l15 == 0) { scw0[pp][wv][quad * 4 + r] = p0; scw1[pp][wv][quad * 4 + r] = p1; }
    }
    __syncthreads();
    {
      int row = wv * 4 + quad, n = m0 + row;
      float s0 = scw0[pp][0][row] + scw0[pp][1][row] + scw0[pp][2][row] + scw0[pp][3][row];
      float s1 = scw1[pp][0][row] + scw1[pp][1][row] + scw1[pp][2][row] + scw1[pp][3][row];
      float mx = fmaxf(s0, s1);
      float e0 = __expf(s0 - mx), e1 = __expf(s1 - mx);
      float inv = 1.f / (e0 + e1);
      float b0 = e0 * inv, b1 = e1 * inv;
      float a0[4] = {ev0.x, ev0.y, ev0.z, ev0.w};
      float a1[4] = {ev1.x, ev1.y, ev1.z, ev1.w};
      float pc0 = 0.f, pc1 = 0.f;
      #pragma unroll
      for (int c = 0; c < 4; ++c) {
        int o = l15 * 4 + c;
        float fv = b0 * a0[c] + b1 * a1[c];
        pc0 += fcw_s[o] * a0[c] + fcw_s[64 + o] * a1[c] + fcw_s[128 + o] * fv;
        pc1 += fcw_s[192 + o] * a0[c] + fcw_s[256 + o] * a1[c] + fcw_s[320 + o] * fv;
      }
      #pragma unroll
      for (int m = 1; m < 16; m <<= 1) { pc0 += __shfl_xor(pc0, m, 64); pc1 += __shfl_xor(pc1, m, 64); }
      if (l15 == 0) {
        float l0 = pc0 + fcb_s[0], l1 = pc1 + fcb_s[1];
        float lm = fmaxf(l0, l1);
        float lse = lm + logf(__expf(l0 - lm) + __expf(l1 - lm));
        out[n * 2] = l0 - lse;
        out[n * 2 + 1] = l1 - lse;
      }
    }
    pp ^= 1;                                // no trailing barrier: next tile writes other buffer
  }
}

extern "C" void kernel_launch(void* const* d_in, const int* in_sizes, int n_in,
                              void* d_out, int out_size, void* d_ws, size_t ws_size,
                              hipStream_t stream)
{
  const float* h     = (const float*)d_in[0];
  const int*   src0  = (const int*)d_in[1];
  const int*   trg0  = (const int*)d_in[2];
  const int*   src1  = (const int*)d_in[3];
  const int*   trg1  = (const int*)d_in[4];
  const float* w0    = (const float*)d_in[5];
  const float* asrc0 = (const float*)d_in[6];
  const float* atrg0 = (const float*)d_in[7];
  const float* w1    = (const float*)d_in[8];
  const float* asrc1 = (const float*)d_in[9];
  const float* atrg1 = (const float*)d_in[10];
  const float* aa_w1 = (const float*)d_in[11];
  const float* aa_w2 = (const float*)d_in[12];
  const float* aa_m  = (const float*)d_in[13];
  const float* fc_w  = (const float*)d_in[14];
  const float* fc_b  = (const float*)d_in[15];
  float* out = (float*)d_out;

  // both-layers-resident needs ~128 MB now (no wgt buffer); fall back if ws is tight
  const int nl = (ws_size >= (size_t)140 * 1024 * 1024) ? 2 : 1;
  const size_t L = (size_t)(nl - 1);   // 1 in concurrent mode, 0 in fallback

  char* ws = (char*)d_ws;
  size_t off = 0;
  auto alloc = [&](size_t bytes) -> void* {
    void* p = ws + off;
    off = (off + bytes + 255) & ~(size_t)255;
    return p;
  };
  uint*   hpi      = (uint*)alloc((size_t)nl * N_NODES * 64 * 4);
  float*  attn_src = (float*)alloc((size_t)nl * N_NODES * 2 * 4);
  float*  attn_trg = (float*)alloc((size_t)nl * N_NODES * 2 * 4);
  float*  x0       = (float*)alloc((size_t)N_USER * 64 * 4);
  float*  x1       = (float*)alloc((size_t)N_USER * 64 * 4);
  int*    offs     = (int*)alloc((size_t)nl * (N_USER + 1) * 4);
  int*    csr      = (int*)alloc((size_t)nl * N_EDGES * 4);
  uint*   pairbuf  = (uint*)alloc((size_t)nl * N_EDGES * 4);    // packed 4B entries
  int*    bhist    = (int*)alloc((size_t)2 * NBUCK * 4);
  int*    bstart   = (int*)alloc((size_t)2 * (NBUCK + 1) * 4);
  int*    bcur     = (int*)alloc((size_t)2 * NBUCK * 16 * 4);

  uint*   hpi1     = hpi + L * (size_t)N_NODES * 64;
  float*  attns1   = attn_src + L * (size_t)N_NODES * 2;
  float*  attnt1   = attn_trg + L * (size_t)N_NODES * 2;
  int*    offs1    = offs + L * (size_t)(N_USER + 1);
  int*    csr1     = csr + L * (size_t)N_EDGES;
  uint*   pairbuf1 = pairbuf + L * (size_t)N_EDGES;

  if (nl == 2) {
    hipMemsetAsync(bhist, 0, (size_t)2 * NBUCK * 4, stream);
    hipLaunchKernelGGL(stage1, dim3(2 * HPB + 2 * TBLK), dim3(256), 0, stream,
                       h, w0, w1, asrc0, asrc1, atrg0, atrg1,
                       hpi, hpi1, attn_src, attns1, attn_trg, attnt1,
                       trg0, trg1, bhist, 2 * HPB, HPB, TBLK);
    hipLaunchKernelGGL(scanb2, dim3(2), dim3(256), 0, stream, bhist, bstart, bcur);
    hipLaunchKernelGGL(bucket2, dim3(2 * TBLK), dim3(1024), 0, stream,
                       src0, src1, trg0, trg1, bcur, pairbuf, pairbuf1, TBLK);
    hipLaunchKernelGGL(fine2, dim3(2 * NBUCK), dim3(1024), 0, stream,
                       pairbuf, pairbuf1, bstart, offs, offs1, csr, csr1, NBUCK);
    hipLaunchKernelGGL(accum2, dim3(2 * ACCB), dim3(256), 0, stream,
                       offs, offs1, csr, csr1, attn_src, attns1, attn_trg, attnt1,
                       hpi, hpi1, x0, x1, ACCB, 1);
  } else {
    for (int layer = 0; layer < 2; ++layer) {
      const float* w    = layer ? w1 : w0;
      const float* asrc = layer ? asrc1 : asrc0;
      const float* atrg = layer ? atrg1 : atrg0;
      const int*   src  = layer ? src1 : src0;
      const int*   trg  = layer ? trg1 : trg0;
      float*       x    = layer ? x1 : x0;
      hipMemsetAsync(bhist, 0, (size_t)NBUCK * 4, stream);
      hipLaunchKernelGGL(stage1, dim3(HPB + TBLK), dim3(256), 0, stream,
                         h, w, w, asrc, asrc, atrg, atrg,
                         hpi, hpi, attn_src, attn_src, attn_trg, attn_trg,
                         trg, trg, bhist, HPB, HPB, TBLK);
      hipLaunchKernelGGL(scanb2, dim3(1), dim3(256), 0, stream, bhist, bstart, bcur);
      hipLaunchKernelGGL(bucket2, dim3(TBLK), dim3(1024), 0, stream,
                         src, src, trg, trg, bcur, pairbuf, pairbuf, TBLK);
      hipLaunchKernelGGL(fine2, dim3(NBUCK), dim3(1024), 0, stream,
                         pairbuf, pairbuf, bstart, offs, offs, csr, csr, NBUCK);
      hipLaunchKernelGGL(accum2, dim3(ACCB), dim3(256), 0, stream,
                         offs, offs, csr, csr, attn_src, attn_src, attn_trg, attn_trg,
                         hpi, hpi, x, x, ACCB, 0);
    }
  }
  hipLaunchKernelGGL(final_mfma, dim3(1875), dim3(256), 0, stream,
                     h, x0, x1, aa_w1, aa_w2, aa_m, fc_w, fc_b, out);
}

// Round 18
// 399.908 us; speedup vs baseline: 1.0766x; 1.0016x over previous
//
#include <hip/hip_runtime.h>
#include <hip/hip_bf16.h>
#include <math.h>

#define N_NODES 100000
#define N_EDGES 1600000
#define N_USER  90000
#define NBUCK   256
#define BSZ     352   // targets per bucket; 256*352 = 90112 >= N_USER
#define TILE    2048  // edges per bucket/bhist block
#define TBLK    782   // (N_EDGES + TILE - 1) / TILE
#define ACCB    22500 // N_USER / 4
#define HPB     1024  // hp base grid (per layer)

typedef __attribute__((ext_vector_type(8))) short  short8;   // 8 bf16 (4 VGPRs) MFMA A/B frag
typedef __attribute__((ext_vector_type(4))) float  floatx4;  // MFMA C/D frag
typedef unsigned int  uint;
typedef unsigned short ushort;

__device__ __forceinline__ ushort f2bf(float x) {            // RNE fp32 -> bf16
  uint u = __float_as_uint(x);
  u += 0x7fffu + ((u >> 16) & 1u);
  return (ushort)(u >> 16);
}
__device__ __forceinline__ float bf2f(ushort v) { return __uint_as_float(((uint)v) << 16); }

__device__ __forceinline__ void split8(const float v[8], short8& hi, short8& lo) {
  #pragma unroll
  for (int j = 0; j < 8; ++j) {
    ushort h = f2bf(v[j]);
    hi[j] = (short)h;
    lo[j] = (short)f2bf(v[j] - bf2f(h));
  }
}
__device__ __forceinline__ void load_split8(const float* p, short8& hi, short8& lo) {
  const float4* q = (const float4*)p;
  float4 a = q[0], b = q[1];
  float v[8] = {a.x, a.y, a.z, a.w, b.x, b.y, b.z, b.w};
  split8(v, hi, lo);
}
__device__ __forceinline__ float fast_tanh(float x) {
  float t = __expf(2.f * x);
  return 1.f - 2.f / (t + 1.f);
}

// ---------------- stage1: hp (MFMA) for both layers  ||  bhist for both layers ----------
__global__ __launch_bounds__(256) void stage1(
    const float* __restrict__ h,
    const float* __restrict__ wA,  const float* __restrict__ wB,
    const float* __restrict__ asA, const float* __restrict__ asB,
    const float* __restrict__ atA, const float* __restrict__ atB,
    uint* __restrict__ hpiA, uint* __restrict__ hpiB,
    float* __restrict__ attnsA, float* __restrict__ attnsB,
    float* __restrict__ attntA, float* __restrict__ attntB,
    const int* __restrict__ trgA, const int* __restrict__ trgB,
    int* __restrict__ bhist,
    int hpTot, int hpBase, int bhBase)
{
  __shared__ float part[4][16][4];          // hp: [wave][row][as0,as1,at0,at1]
  __shared__ int hh[NBUCK];                 // bhist
  const int tid = threadIdx.x;

  if (blockIdx.x >= hpTot) {                // ---- bhist branch ----
    const int b2 = blockIdx.x - hpTot;
    const int layer = (b2 >= bhBase) ? 1 : 0;
    const int bid = b2 - layer * bhBase;
    const int* trg = layer ? trgB : trgA;
    int* bh = bhist + layer * NBUCK;
    hh[tid] = 0;
    __syncthreads();
    const int b0 = bid * TILE;
    #pragma unroll
    for (int j = 0; j < 8; ++j) {
      int e = b0 + j * 256 + tid;
      if (e < N_EDGES) {
        int t = trg[e];
        if (t < N_USER) atomicAdd(&hh[t / BSZ], 1);
      }
    }
    __syncthreads();
    if (hh[tid]) atomicAdd(&bh[tid], hh[tid]);
    return;
  }

  // ---- hp branch ----
  const int layer = (blockIdx.x >= hpBase) ? 1 : 0;
  const int bid = blockIdx.x - layer * hpBase;
  const float* w     = layer ? wB : wA;
  const float* a_src = layer ? asB : asA;
  const float* a_trg = layer ? atB : atA;
  uint*  hpi      = layer ? hpiB : hpiA;
  float* attn_src = layer ? attnsB : attnsA;
  float* attn_trg = layer ? attntB : attntA;

  const int lane = tid & 63, wv = tid >> 6;
  const int quad = lane >> 4, l15 = lane & 15;
  const int o = wv * 16 + l15;              // wave's 16-col slice of the 64 outputs
  const float vas0 = a_src[o], vas1 = a_src[64 + o];
  const float vat0 = a_trg[o], vat1 = a_trg[64 + o];
  short8 b0h[2], b0l[2], b1h[2], b1l[2];    // B frags: head0/head1 x ksteps
  #pragma unroll
  for (int ks = 0; ks < 2; ++ks) {
    float v0[8], v1[8];
    #pragma unroll
    for (int j = 0; j < 8; ++j) {
      int k = quad * 8 + j + ks * 32;       // f index
      v0[j] = w[k * 64 + o];                // w[0][f][o]
      v1[j] = w[4096 + k * 64 + o];         // w[1][f][o]
    }
    split8(v0, b0h[ks], b0l[ks]);
    split8(v1, b1h[ks], b1l[ks]);
  }
  for (int t = bid; t < N_NODES / 16; t += hpBase) {
    int m0 = t * 16, arow = m0 + l15;
    short8 ah[2], al[2];
    #pragma unroll
    for (int ks = 0; ks < 2; ++ks)
      load_split8(h + arow * 64 + quad * 8 + ks * 32, ah[ks], al[ks]);
    floatx4 c0 = {0.f, 0.f, 0.f, 0.f}, c1 = {0.f, 0.f, 0.f, 0.f};
    #pragma unroll
    for (int ks = 0; ks < 2; ++ks) {
      c0 = __builtin_amdgcn_mfma_f32_16x16x32_bf16(ah[ks], b0h[ks], c0, 0, 0, 0);
      c0 = __builtin_amdgcn_mfma_f32_16x16x32_bf16(ah[ks], b0l[ks], c0, 0, 0, 0);
      c0 = __builtin_amdgcn_mfma_f32_16x16x32_bf16(al[ks], b0h[ks], c0, 0, 0, 0);
      c1 = __builtin_amdgcn_mfma_f32_16x16x32_bf16(ah[ks], b1h[ks], c1, 0, 0, 0);
      c1 = __builtin_amdgcn_mfma_f32_16x16x32_bf16(ah[ks], b1l[ks], c1, 0, 0, 0);
      c1 = __builtin_amdgcn_mfma_f32_16x16x32_bf16(al[ks], b1h[ks], c1, 0, 0, 0);
    }
    #pragma unroll
    for (int r = 0; r < 4; ++r) {
      int n = m0 + quad * 4 + r;
      hpi[n * 64 + o] = (uint)f2bf(c0[r]) | ((uint)f2bf(c1[r]) << 16);
    }
    #pragma unroll
    for (int r = 0; r < 4; ++r) {
      float pas0 = c0[r] * vas0, pas1 = c1[r] * vas1;
      float pat0 = c0[r] * vat0, pat1 = c1[r] * vat1;
      #pragma unroll
      for (int m = 1; m < 16; m <<= 1) {
        pas0 += __shfl_xor(pas0, m, 64); pas1 += __shfl_xor(pas1, m, 64);
        pat0 += __shfl_xor(pat0, m, 64); pat1 += __shfl_xor(pat1, m, 64);
      }
      if (l15 == 0) {
        part[wv][quad * 4 + r][0] = pas0; part[wv][quad * 4 + r][1] = pas1;
        part[wv][quad * 4 + r][2] = pat0; part[wv][quad * 4 + r][3] = pat1;
      }
    }
    __syncthreads();
    if (tid < 64) {
      int row = tid & 15, which = tid >> 4;
      float v = part[0][row][which] + part[1][row][which]
              + part[2][row][which] + part[3][row][which];
      int n = m0 + row;
      if (which == 0)      attn_src[n * 2]     = v;
      else if (which == 1) attn_src[n * 2 + 1] = v;
      else if (which == 2) attn_trg[n * 2]     = v;
      else                 attn_trg[n * 2 + 1] = v;
    }
    __syncthreads();
  }
}

// 1-block-per-layer scan of the 256 bucket sizes -> bstart[257] + seeded bucket cursors.
__global__ __launch_bounds__(256) void scanb2(const int* __restrict__ bhist,
                                              int* __restrict__ bstart, int* __restrict__ bcur)
{
  const int layer = blockIdx.x;
  const int* bh = bhist + layer * NBUCK;
  int* bs = bstart + layer * (NBUCK + 1);
  int* bc = bcur + layer * NBUCK * 16;
  __shared__ int s[256];
  int v = bh[threadIdx.x];
  s[threadIdx.x] = v;
  __syncthreads();
  for (int d = 1; d < 256; d <<= 1) {
    int t = (threadIdx.x >= d) ? s[threadIdx.x - d] : 0;
    __syncthreads();
    s[threadIdx.x] += t;
    __syncthreads();
  }
  int excl = s[threadIdx.x] - v;
  bs[threadIdx.x] = excl;
  bc[threadIdx.x * 16] = excl;
  if (threadIdx.x == 255) bs[256] = s[255];
}

// Pass B: bin a 2048-edge tile by bucket in LDS (R15-proven 1024-thread version).
__global__ __launch_bounds__(1024) void bucket2(
    const int* __restrict__ srcA, const int* __restrict__ srcB,
    const int* __restrict__ trgA, const int* __restrict__ trgB,
    int* __restrict__ bcur, uint* __restrict__ pairbufA, uint* __restrict__ pairbufB, int base)
{
  const int layer = (blockIdx.x >= base) ? 1 : 0;
  const int bid = blockIdx.x - layer * base;
  const int* src = layer ? srcB : srcA;
  const int* trg = layer ? trgB : trgA;
  int* bc = bcur + layer * NBUCK * 16;
  uint* pairbuf = layer ? pairbufB : pairbufA;

  __shared__ uint2 plds[TILE];              // (packed entry, bucket id)
  __shared__ int bcnt[NBUCK], bscan[NBUCK], gbase[NBUCK];
  const int tid = threadIdx.x;
  const int b0 = bid * TILE;
  if (tid < NBUCK) bcnt[tid] = 0;
  __syncthreads();
  int myb[2], myr[2];
  uint myp[2];
  #pragma unroll
  for (int j = 0; j < 2; ++j) {
    int e = b0 + j * 1024 + tid;
    myb[j] = -1;
    if (e < N_EDGES) {
      int t = trg[e];
      if (t < N_USER) {
        int b = t / BSZ;
        int tl = t - b * BSZ;               // < 352, fits 9 bits
        myb[j] = b;
        myr[j] = atomicAdd(&bcnt[b], 1);
        myp[j] = (uint)src[e] | ((uint)tl << 17);   // src < 2^17
      }
    }
  }
  __syncthreads();
  if (tid < NBUCK) {
    gbase[tid] = atomicAdd(&bc[tid * 16], bcnt[tid]);
    bscan[tid] = bcnt[tid];
  }
  __syncthreads();
  for (int d = 1; d < 256; d <<= 1) {
    int v = (tid >= d && tid < NBUCK) ? bscan[tid - d] : 0;
    __syncthreads();
    if (tid < NBUCK) bscan[tid] += v;
    __syncthreads();
  }
  #pragma unroll
  for (int j = 0; j < 2; ++j)
    if (myb[j] >= 0) plds[bscan[myb[j]] - bcnt[myb[j]] + myr[j]] = make_uint2(myp[j], (uint)myb[j]);
  __syncthreads();
  int total = bscan[NBUCK - 1];
  for (int i = tid; i < total; i += 1024) {
    uint2 pr = plds[i];
    int b = (int)pr.y;
    int idx = gbase[b] + (i - (bscan[b] - bcnt[b]));
    if (idx >= 0 && idx < N_EDGES) pairbuf[idx] = pr.x;
  }
}

// Pass C (R26): pure count/scan/scatter. 1024 threads.
__global__ __launch_bounds__(1024) void fine2(
    const uint* __restrict__ pairbufA, const uint* __restrict__ pairbufB,
    const int* __restrict__ bstart,
    int* __restrict__ offsA, int* __restrict__ offsB,
    int* __restrict__ csrA,  int* __restrict__ csrB, int base)
{
  const int layer = (blockIdx.x >= base) ? 1 : 0;
  const int b = blockIdx.x - layer * base;
  const uint* pairbuf = layer ? pairbufB : pairbufA;
  const int* bs = bstart + layer * (NBUCK + 1);
  int* offs = layer ? offsB : offsA;
  int* csr_src = layer ? csrB : csrA;

  __shared__ int cnt[BSZ + 1];
  __shared__ int cur[BSZ];
  const int tid = threadIdx.x;
  const int t0 = b * BSZ;
  const int nt = min(BSZ, N_USER - t0);     // 240 for bucket 255
  const int pbeg = bs[b], pend = bs[b + 1];
  for (int j = tid; j <= BSZ; j += 1024) cnt[j] = 0;
  __syncthreads();
  for (int i = pbeg + tid; i < pend; i += 1024) {
    int tl = min((int)(pairbuf[i] >> 17), BSZ - 1);
    atomicAdd(&cnt[tl], 1);
  }
  __syncthreads();
  if (tid == 0) {                           // serial exclusive scan, <=352 elems
    int run = 0;
    for (int j = 0; j < nt; ++j) { int c = cnt[j]; cnt[j] = run; run += c; }
    cnt[nt] = run;
  }
  __syncthreads();
  for (int j = tid; j < nt; j += 1024) {
    offs[t0 + j] = pbeg + cnt[j];
    cur[j] = cnt[j];
  }
  if (tid == 0 && t0 + nt == N_USER) offs[N_USER] = pbeg + cnt[nt];
  __syncthreads();
  for (int i = pbeg + tid; i < pend; i += 1024) {
    uint v = pairbuf[i];
    int s = min((int)(v & 0x1FFFFu), N_NODES - 1);
    int tl = min((int)(v >> 17), BSZ - 1);
    int p = pbeg + atomicAdd(&cur[tl], 1);
    p = min(max(p, 0), N_EDGES - 1);
    csr_src[p] = s;
  }
}

// ---------------- per-target accumulation (R26: weights computed in-kernel) ------------
__global__ __launch_bounds__(256) void accum2(
    const int* __restrict__ offsA, const int* __restrict__ offsB,
    const int* __restrict__ csrA,  const int* __restrict__ csrB,
    const float* __restrict__ attnsA, const float* __restrict__ attnsB,
    const float* __restrict__ attntA, const float* __restrict__ attntB,
    const uint* __restrict__ hpiA, const uint* __restrict__ hpiB,
    float* __restrict__ xA, float* __restrict__ xB, int base, int swz)
{
  int layer, bid;
  if (swz) {
    const int xcd = blockIdx.x & 7, idx = blockIdx.x >> 3;
    layer = xcd >> 2;
    bid = idx * 4 + (xcd & 3);
  } else {
    layer = (blockIdx.x >= base) ? 1 : 0;
    bid = blockIdx.x - layer * base;
  }
  const int* offs = layer ? offsB : offsA;
  const int* csr_src = layer ? csrB : csrA;
  const float2* as2 = (const float2*)(layer ? attnsB : attnsA);
  const float2* at2 = (const float2*)(layer ? attntB : attntA);
  const uint* hpi = layer ? hpiB : hpiA;
  float* x = layer ? xB : xA;

  const int lane = threadIdx.x & 63, wv = threadIdx.x >> 6;
  int n = bid * 4 + wv;
  if (n >= N_USER) return;
  int beg = max(0, offs[n]);
  int end = min(offs[n + 1], N_EDGES);
  beg = __builtin_amdgcn_readfirstlane(beg);   // wave-uniform by construction
  end = __builtin_amdgcn_readfirstlane(end);
  int deg = end - beg;
  const float2 at = at2[n];                    // wave-uniform target logit
  float acc0 = 0.f, acc1 = 0.f, den0 = 0.f, den1 = 0.f;
  for (int base2 = 0; base2 < deg; base2 += 64) {
    int rem = min(64, deg - base2);
    int sv = csr_src[beg + base2 + min(lane, rem - 1)];  // coalesced; lanes>=rem dup last
    sv = min(max(sv, 0), N_NODES - 1);                   // clamp once, pre-broadcast
    // per-lane weight for edge base2+lane (ghost lanes carry 0)
    float2 as = as2[sv];
    float e0 = as.x + at.x; e0 = (e0 > 0.f) ? e0 : 0.2f * e0;
    float e1 = as.y + at.y; e1 = (e1 > 0.f) ? e1 : 0.2f * e1;
    float wx = (lane < rem) ? __expf(e0) : 0.f;
    float wy = (lane < rem) ? __expf(e1) : 0.f;
    {                                                    // den: butterfly (ghosts = 0)
      float dx = wx, dy = wy;
      #pragma unroll
      for (int m = 1; m < 64; m <<= 1) { dx += __shfl_xor(dx, m, 64); dy += __shfl_xor(dy, m, 64); }
      den0 += dx; den1 += dy;
    }
    const int wxi = __float_as_int(wx), wyi = __float_as_int(wy);
    for (int j = 0; j < rem; j += 8) {                   // uniform lean 8-wide blocks
      int ss[8]; uint pv[8]; float Wx[8], Wy[8];
      #pragma unroll
      for (int u = 0; u < 8; ++u) ss[u] = __builtin_amdgcn_readlane(sv, j + u);  // SGPR
      #pragma unroll
      for (int u = 0; u < 8; ++u) pv[u] = (hpi + (size_t)ss[u] * 64)[lane];      // saddr
      #pragma unroll
      for (int u = 0; u < 8; ++u) {
        Wx[u] = __int_as_float(__builtin_amdgcn_readlane(wxi, j + u));
        Wy[u] = __int_as_float(__builtin_amdgcn_readlane(wyi, j + u));
      }
      #pragma unroll
      for (int u = 0; u < 8; ++u) {
        acc0 += Wx[u] * bf2f((ushort)(pv[u] & 0xffffu));
        acc1 += Wy[u] * bf2f((ushort)(pv[u] >> 16));
      }
    }
  }
  x[n * 64 + lane] = 0.5f * (acc0 / (den0 + 1e-16f) + acc1 / (den1 + 1e-16f));
}

// ---------------- final: 3 MFMA GEMMs + fused epilogue (R10-verbatim, barrier diet) -----
__global__ __launch_bounds__(256) void final_mfma(
    const float* __restrict__ h, const float* __restrict__ x0, const float* __restrict__ x1,
    const float* __restrict__ aa_w1, const float* __restrict__ aa_w2, const float* __restrict__ aa_m,
    const float* __restrict__ fc_w, const float* __restrict__ fc_b, float* __restrict__ out)
{
  __shared__ float aam_s[64], fcw_s[384], fcb_s[2];
  __shared__ float scw0[2][4][16], scw1[2][4][16];
  const int tid = threadIdx.x;
  if (tid < 64)  aam_s[tid] = aa_m[tid];
  for (int i = tid; i < 384; i += 256) fcw_s[i] = fc_w[i];
  if (tid < 2)   fcb_s[tid] = fc_b[tid];
  const int lane = tid & 63, wv = tid >> 6, quad = lane >> 4, l15 = lane & 15;
  const int d = wv * 16 + l15;
  short8 b1h[2], b1l[2], b2h[2], b2l[2];
  #pragma unroll
  for (int ks = 0; ks < 2; ++ks) {
    load_split8(aa_w1 + d * 64 + quad * 8 + ks * 32, b1h[ks], b1l[ks]);
    load_split8(aa_w2 + d * 64 + quad * 8 + ks * 32, b2h[ks], b2l[ks]);
  }
  __syncthreads();
  int pp = 0;
  for (int t = blockIdx.x; t < N_USER / 16; t += gridDim.x) {
    int m0 = t * 16, arow = m0 + l15;
    const int erow = m0 + wv * 4 + quad;
    float4 ev0 = *(const float4*)(x0 + erow * 64 + l15 * 4);
    float4 ev1 = *(const float4*)(x1 + erow * 64 + l15 * 4);
    short8 ahh[2], ahl[2], a0h[2], a0l[2], a1h[2], a1l[2];
    #pragma unroll
    for (int ks = 0; ks < 2; ++ks) {
      load_split8(h  + arow * 64 + quad * 8 + ks * 32, ahh[ks], ahl[ks]);
      load_split8(x0 + arow * 64 + quad * 8 + ks * 32, a0h[ks], a0l[ks]);
      load_split8(x1 + arow * 64 + quad * 8 + ks * 32, a1h[ks], a1l[ks]);
    }
    floatx4 t1a = {0.f,0.f,0.f,0.f}, t20a = {0.f,0.f,0.f,0.f}, t21a = {0.f,0.f,0.f,0.f};
    #pragma unroll
    for (int ks = 0; ks < 2; ++ks) {
      t1a  = __builtin_amdgcn_mfma_f32_16x16x32_bf16(ahh[ks], b1h[ks], t1a, 0, 0, 0);
      t1a  = __builtin_amdgcn_mfma_f32_16x16x32_bf16(ahh[ks], b1l[ks], t1a, 0, 0, 0);
      t1a  = __builtin_amdgcn_mfma_f32_16x16x32_bf16(ahl[ks], b1h[ks], t1a, 0, 0, 0);
      t20a = __builtin_amdgcn_mfma_f32_16x16x32_bf16(a0h[ks], b2h[ks], t20a, 0, 0, 0);
      t20a = __builtin_amdgcn_mfma_f32_16x16x32_bf16(a0h[ks], b2l[ks], t20a, 0, 0, 0);
      t20a = __builtin_amdgcn_mfma_f32_16x16x32_bf16(a0l[ks], b2h[ks], t20a, 0, 0, 0);
      t21a = __builtin_amdgcn_mfma_f32_16x16x32_bf16(a1h[ks], b2h[ks], t21a, 0, 0, 0);
      t21a = __builtin_amdgcn_mfma_f32_16x16x32_bf16(a1h[ks], b2l[ks], t21a, 0, 0, 0);
      t21a = __builtin_amdgcn_mfma_f32_16x16x32_bf16(a1l[ks], b2h[ks], t21a, 0, 0, 0);
    }
    float am = aam_s[d];
    #pragma unroll
    for (int r = 0; r < 4; ++r) {
      float q0 = fast_tanh(t1a[r] + t20a[r]);
      float q1 = fast_tanh(t1a[r] + t21a[r]);
      float p0 = q0 * am, p1 = q1 * am;
      #pragma unroll
      for (int m = 1; m < 16; m <<= 1) { p0 += __shfl_xor(p0, m, 64); p1 += __shfl_xor(p1, m, 64); }
      if (l15 == 0) { scw0[pp][wv][quad * 4 + r] = p0; scw1[pp][wv][quad * 4 + r] = p1; }
    }
    __syncthreads();
    {
      int row = wv * 4 + quad, n = m0 + row;
      float s0 = scw0[pp][0][row] + scw0[pp][1][row] + scw0[pp][2][row] + scw0[pp][3][row];
      float s1 = scw1[pp][0][row] + scw1[pp][1][row] + scw1[pp][2][row] + scw1[pp][3][row];
      float mx = fmaxf(s0, s1);
      float e0 = __expf(s0 - mx), e1 = __expf(s1 - mx);
      float inv = 1.f / (e0 + e1);
      float b0 = e0 * inv, b1 = e1 * inv;
      float a0[4] = {ev0.x, ev0.y, ev0.z, ev0.w};
      float a1[4] = {ev1.x, ev1.y, ev1.z, ev1.w};
      float pc0 = 0.f, pc1 = 0.f;
      #pragma unroll
      for (int c = 0; c < 4; ++c) {
        int o = l15 * 4 + c;
        float fv = b0 * a0[c] + b1 * a1[c];
        pc0 += fcw_s[o] * a0[c] + fcw_s[64 + o] * a1[c] + fcw_s[128 + o] * fv;
        pc1 += fcw_s[192 + o] * a0[c] + fcw_s[256 + o] * a1[c] + fcw_s[320 + o] * fv;
      }
      #pragma unroll
      for (int m = 1; m < 16; m <<= 1) { pc0 += __shfl_xor(pc0, m, 64); pc1 += __shfl_xor(pc1, m, 64); }
      if (l15 == 0) {
        float l0 = pc0 + fcb_s[0], l1 = pc1 + fcb_s[1];
        float lm = fmaxf(l0, l1);
        float lse = lm + logf(__expf(l0 - lm) + __expf(l1 - lm));
        out[n * 2] = l0 - lse;
        out[n * 2 + 1] = l1 - lse;
      }
    }
    pp ^= 1;                                // no trailing barrier: next tile writes other buffer
  }
}

extern "C" void kernel_launch(void* const* d_in, const int* in_sizes, int n_in,
                              void* d_out, int out_size, void* d_ws, size_t ws_size,
                              hipStream_t stream)
{
  const float* h     = (const float*)d_in[0];
  const int*   src0  = (const int*)d_in[1];
  const int*   trg0  = (const int*)d_in[2];
  const int*   src1  = (const int*)d_in[3];
  const int*   trg1  = (const int*)d_in[4];
  const float* w0    = (const float*)d_in[5];
  const float* asrc0 = (const float*)d_in[6];
  const float* atrg0 = (const float*)d_in[7];
  const float* w1    = (const float*)d_in[8];
  const float* asrc1 = (const float*)d_in[9];
  const float* atrg1 = (const float*)d_in[10];
  const float* aa_w1 = (const float*)d_in[11];
  const float* aa_w2 = (const float*)d_in[12];
  const float* aa_m  = (const float*)d_in[13];
  const float* fc_w  = (const float*)d_in[14];
  const float* fc_b  = (const float*)d_in[15];
  float* out = (float*)d_out;

  // both-layers-resident needs ~128 MB (no wgt buffer); fall back if ws is tight
  const int nl = (ws_size >= (size_t)140 * 1024 * 1024) ? 2 : 1;
  const size_t L = (size_t)(nl - 1);   // 1 in concurrent mode, 0 in fallback

  char* ws = (char*)d_ws;
  size_t off = 0;
  auto alloc = [&](size_t bytes) -> void* {
    void* p = ws + off;
    off = (off + bytes + 255) & ~(size_t)255;
    return p;
  };
  uint*   hpi      = (uint*)alloc((size_t)nl * N_NODES * 64 * 4);
  float*  attn_src = (float*)alloc((size_t)nl * N_NODES * 2 * 4);
  float*  attn_trg = (float*)alloc((size_t)nl * N_NODES * 2 * 4);
  float*  x0       = (float*)alloc((size_t)N_USER * 64 * 4);
  float*  x1       = (float*)alloc((size_t)N_USER * 64 * 4);
  int*    offs     = (int*)alloc((size_t)nl * (N_USER + 1) * 4);
  int*    csr      = (int*)alloc((size_t)nl * N_EDGES * 4);
  uint*   pairbuf  = (uint*)alloc((size_t)nl * N_EDGES * 4);    // packed 4B entries
  int*    bhist    = (int*)alloc((size_t)2 * NBUCK * 4);
  int*    bstart   = (int*)alloc((size_t)2 * (NBUCK + 1) * 4);
  int*    bcur     = (int*)alloc((size_t)2 * NBUCK * 16 * 4);

  uint*   hpi1     = hpi + L * (size_t)N_NODES * 64;
  float*  attns1   = attn_src + L * (size_t)N_NODES * 2;
  float*  attnt1   = attn_trg + L * (size_t)N_NODES * 2;
  int*    offs1    = offs + L * (size_t)(N_USER + 1);
  int*    csr1     = csr + L * (size_t)N_EDGES;
  uint*   pairbuf1 = pairbuf + L * (size_t)N_EDGES;

  if (nl == 2) {
    hipMemsetAsync(bhist, 0, (size_t)2 * NBUCK * 4, stream);
    hipLaunchKernelGGL(stage1, dim3(2 * HPB + 2 * TBLK), dim3(256), 0, stream,
                       h, w0, w1, asrc0, asrc1, atrg0, atrg1,
                       hpi, hpi1, attn_src, attns1, attn_trg, attnt1,
                       trg0, trg1, bhist, 2 * HPB, HPB, TBLK);
    hipLaunchKernelGGL(scanb2, dim3(2), dim3(256), 0, stream, bhist, bstart, bcur);
    hipLaunchKernelGGL(bucket2, dim3(2 * TBLK), dim3(1024), 0, stream,
                       src0, src1, trg0, trg1, bcur, pairbuf, pairbuf1, TBLK);
    hipLaunchKernelGGL(fine2, dim3(2 * NBUCK), dim3(1024), 0, stream,
                       pairbuf, pairbuf1, bstart, offs, offs1, csr, csr1, NBUCK);
    hipLaunchKernelGGL(accum2, dim3(2 * ACCB), dim3(256), 0, stream,
                       offs, offs1, csr, csr1, attn_src, attns1, attn_trg, attnt1,
                       hpi, hpi1, x0, x1, ACCB, 1);
  } else {
    for (int layer = 0; layer < 2; ++layer) {
      const float* w    = layer ? w1 : w0;
      const float* asrc = layer ? asrc1 : asrc0;
      const float* atrg = layer ? atrg1 : atrg0;
      const int*   src  = layer ? src1 : src0;
      const int*   trg  = layer ? trg1 : trg0;
      float*       x    = layer ? x1 : x0;
      hipMemsetAsync(bhist, 0, (size_t)NBUCK * 4, stream);
      hipLaunchKernelGGL(stage1, dim3(HPB + TBLK), dim3(256), 0, stream,
                         h, w, w, asrc, asrc, atrg, atrg,
                         hpi, hpi, attn_src, attn_src, attn_trg, attn_trg,
                         trg, trg, bhist, HPB, HPB, TBLK);
      hipLaunchKernelGGL(scanb2, dim3(1), dim3(256), 0, stream, bhist, bstart, bcur);
      hipLaunchKernelGGL(bucket2, dim3(TBLK), dim3(1024), 0, stream,
                         src, src, trg, trg, bcur, pairbuf, pairbuf, TBLK);
      hipLaunchKernelGGL(fine2, dim3(NBUCK), dim3(1024), 0, stream,
                         pairbuf, pairbuf, bstart, offs, offs, csr, csr, NBUCK);
      hipLaunchKernelGGL(accum2, dim3(ACCB), dim3(256), 0, stream,
                         offs, offs, csr, csr, attn_src, attn_src, attn_trg, attn_trg,
                         hpi, hpi, x, x, ACCB, 0);
    }
  }
  hipLaunchKernelGGL(final_mfma, dim3(1875), dim3(256), 0, stream,
                     h, x0, x1, aa_w1, aa_w2, aa_m, fc_w, fc_b, out);
}